// Round 1
// baseline (2496.740 us; speedup 1.0000x reference)
//
#include <hip/hip_runtime.h>
#include <hip/hip_bf16.h>

#define N_NODES 50000
#define N_EDGES 400000
#define N_GRAPHS 64
#define HID 200
#define NUM_OUT 16
#define NLAYERS 5

// ---------------------------------------------------------------------------
// node embedding: x = kind_emb[kind] + (kind==0 ? inst2vec[content] : type_emb)
__global__ void embed_kernel(const int* __restrict__ kind, const int* __restrict__ content,
                             const float* __restrict__ kind_emb, const float* __restrict__ inst2vec,
                             const float* __restrict__ type_emb, float* __restrict__ x) {
  int n = blockIdx.x; int ch = threadIdx.x;
  if (ch >= HID) return;
  int k = kind[n];
  float v = kind_emb[k * HID + ch];
  v += (k == 0) ? inst2vec[(size_t)content[n] * HID + ch] : type_emb[ch];
  x[(size_t)n * HID + ch] = v;
}

// precombined edge embedding table: ecomb[code][c], code = etype*20 + min(pos,19)
__global__ void ecomb_kernel(const float* __restrict__ etype_emb, const float* __restrict__ epos_emb,
                             float* __restrict__ ecomb) {
  int code = blockIdx.x; int ch = threadIdx.x;
  if (ch >= HID) return;
  ecomb[code * HID + ch] = etype_emb[(code / 20) * HID + ch] + epos_emb[(code % 20) * HID + ch];
}

// CSR build: histogram of dst
__global__ void hist_kernel(const int* __restrict__ dst, int* __restrict__ deg) {
  int e = blockIdx.x * 256 + threadIdx.x;
  if (e < N_EDGES) atomicAdd(&deg[dst[e]], 1);
}

// single-block exclusive scan over 50000 degrees -> offs[0..N], cursor copy
__global__ void scan_kernel(const int* __restrict__ deg, int* __restrict__ offs, int* __restrict__ cursor) {
  __shared__ int buf[1024];
  __shared__ int carry_s;
  int tid = threadIdx.x;
  if (tid == 0) carry_s = 0;
  __syncthreads();
  for (int base = 0; base < N_NODES; base += 1024) {
    int i = base + tid;
    int v = (i < N_NODES) ? deg[i] : 0;
    buf[tid] = v;
    __syncthreads();
    for (int off = 1; off < 1024; off <<= 1) {
      int t = (tid >= off) ? buf[tid - off] : 0;
      __syncthreads();
      buf[tid] += t;
      __syncthreads();
    }
    int incl = buf[tid];
    int carry = carry_s;
    if (i < N_NODES) { int excl = carry + incl - v; offs[i] = excl; cursor[i] = excl; }
    __syncthreads();
    if (tid == 1023) carry_s = carry + incl;
    __syncthreads();
  }
  if (tid == 0) offs[N_NODES] = carry_s;
}

// scatter edges into CSR slots (order within a node nondeterministic -> fp noise only)
__global__ void scatter_kernel(const int* __restrict__ src, const int* __restrict__ dst,
                               const int* __restrict__ etype, const int* __restrict__ epos,
                               int* __restrict__ cursor, int* __restrict__ e_src, int* __restrict__ e_code) {
  int e = blockIdx.x * 256 + threadIdx.x;
  if (e >= N_EDGES) return;
  int d = dst[e];
  int slot = atomicAdd(&cursor[d], 1);
  e_src[slot] = src[e];
  int p = epos[e]; if (p > 19) p = 19;
  e_code[slot] = etype[e] * 20 + p;
}

// graph boundaries via binary search over sorted batch_vec
__global__ void gstart_kernel(const int* __restrict__ bv, int* __restrict__ gstart) {
  int g = threadIdx.x;
  if (g > N_GRAPHS) return;
  if (g == N_GRAPHS) { gstart[N_GRAPHS] = N_NODES; return; }
  int lo = 0, hi = N_NODES;
  while (lo < hi) { int mid = (lo + hi) >> 1; if (bv[mid] < g) lo = mid + 1; else hi = mid; }
  gstart[g] = lo;
}

// GINE aggregation: y[n] = x[n] + sum_{e: dst=n} relu(x[src_e] + ecomb[code_e])
__global__ void agg_kernel(const float* __restrict__ x, float* __restrict__ y,
                           const int* __restrict__ offs, const int* __restrict__ e_src,
                           const int* __restrict__ e_code, const float* __restrict__ ecomb) {
  int n = blockIdx.x; int ch = threadIdx.x;
  if (ch >= HID) return;
  int s0 = offs[n], s1 = offs[n + 1];
  float acc = 0.f;
  for (int j = s0; j < s1; ++j) {
    int s = e_src[j]; int code = e_code[j];
    float v = x[(size_t)s * HID + ch] + ecomb[code * HID + ch];
    acc += fmaxf(v, 0.f);
  }
  y[(size_t)n * HID + ch] = x[(size_t)n * HID + ch] + acc;
}

// fp32 GEMM  C[M x 200] = A[M x 200] @ W[200 x 200]  with fused epilogue.
// MODE 1: BN(h + b1) then relu.  MODE 2: +b2 then relu.
// 128-row tile per block, 256 threads, 4 rows x 25 cols per thread.
// In-place safe: each block only reads/writes its own 128 rows.
template<int MODE>
__global__ __launch_bounds__(256) void gemm_kernel(
    const float* __restrict__ A, float* __restrict__ C, const float* __restrict__ W,
    const float* __restrict__ p0, const float* __restrict__ p1, const float* __restrict__ p2,
    const float* __restrict__ p3, const float* __restrict__ p4) {
  __shared__ float A_lds[8][128];
  __shared__ float W_lds[8 * HID];
  int tid = threadIdx.x;
  int r0base = blockIdx.x * 128;
  int cg = tid >> 5, rl = tid & 31;
  int cbase = cg * 25;
  int lrow = tid >> 1, lhalf = (tid & 1) * 4;

  float acc[4][25];
  #pragma unroll
  for (int i = 0; i < 4; ++i)
    #pragma unroll
    for (int j = 0; j < 25; ++j) acc[i][j] = 0.f;

  for (int k0 = 0; k0 < HID; k0 += 8) {
    int grow = r0base + lrow;
    float4 av = make_float4(0.f, 0.f, 0.f, 0.f);
    if (grow < N_NODES) av = *reinterpret_cast<const float4*>(A + (size_t)grow * HID + k0 + lhalf);
    __syncthreads();   // protect previous iteration's LDS reads
    A_lds[lhalf + 0][lrow] = av.x;
    A_lds[lhalf + 1][lrow] = av.y;
    A_lds[lhalf + 2][lrow] = av.z;
    A_lds[lhalf + 3][lrow] = av.w;
    const float4* Wv = reinterpret_cast<const float4*>(W + k0 * HID);
    float4* WL = reinterpret_cast<float4*>(W_lds);
    for (int idx = tid; idx < (8 * HID) / 4; idx += 256) WL[idx] = Wv[idx];
    __syncthreads();
    #pragma unroll
    for (int kk = 0; kk < 8; ++kk) {
      float a0 = A_lds[kk][rl];
      float a1 = A_lds[kk][rl + 32];
      float a2 = A_lds[kk][rl + 64];
      float a3 = A_lds[kk][rl + 96];
      const float* wrow = &W_lds[kk * HID + cbase];
      #pragma unroll
      for (int j = 0; j < 25; ++j) {
        float w = wrow[j];
        acc[0][j] = fmaf(a0, w, acc[0][j]);
        acc[1][j] = fmaf(a1, w, acc[1][j]);
        acc[2][j] = fmaf(a2, w, acc[2][j]);
        acc[3][j] = fmaf(a3, w, acc[3][j]);
      }
    }
  }

  #pragma unroll
  for (int i = 0; i < 4; ++i) {
    int r = r0base + rl + 32 * i;
    if (r < N_NODES) {
      float* crow = C + (size_t)r * HID + cbase;
      #pragma unroll
      for (int j = 0; j < 25; ++j) {
        float v = acc[i][j];
        int c = cbase + j;
        if (MODE == 1) {
          float s = p2[c] * rsqrtf(p3[c] + 1e-5f);
          float t = (p0[c] - p1[c]) * s + p4[c];
          v = fmaf(v, s, t);
        } else {
          v = v + p0[c];
        }
        crow[j] = fmaxf(v, 0.f);
      }
    }
  }
}

// per-graph partial sums (chunked to get parallelism), atomics across 8 chunks
__global__ void pool_kernel(const float* __restrict__ x, float* __restrict__ pool_sum,
                            const int* __restrict__ gstart) {
  int g = blockIdx.x, chunk = blockIdx.y, ch = threadIdx.x;
  if (ch >= HID) return;
  int s = gstart[g], e = gstart[g + 1];
  int len = e - s;
  int per = (len + (int)gridDim.y - 1) / (int)gridDim.y;
  int cs = s + chunk * per; int ce = cs + per; if (ce > e) ce = e;
  if (cs >= ce) return;
  float acc = 0.f;
  for (int n = cs; n < ce; ++n) acc += x[(size_t)n * HID + ch];
  atomicAdd(&pool_sum[g * HID + ch], acc);
}

// jumping-knowledge heads, all 6 layers summed
__global__ void head_kernel(const float* __restrict__ pools, const int* __restrict__ gstart,
                            const float* __restrict__ fcW, const float* __restrict__ fcb,
                            float* __restrict__ out) {
  int tid = threadIdx.x;
  if (tid >= N_GRAPHS * NUM_OUT) return;
  int g = tid >> 4, o = tid & 15;
  int cnt = gstart[g + 1] - gstart[g];
  float inv = 1.f / (float)(cnt > 0 ? cnt : 1);
  float acc = 0.f;
  for (int i = 0; i < NLAYERS + 1; ++i) {
    const float* ps = pools + (size_t)(i * N_GRAPHS + g) * HID;
    const float* w = fcW + (size_t)(i * HID) * NUM_OUT + o;
    float a = 0.f;
    for (int c = 0; c < HID; ++c) a = fmaf(ps[c], w[c * NUM_OUT], a);
    acc += a * inv + fcb[i * NUM_OUT + o];
  }
  out[g * NUM_OUT + o] = acc;
}

// ---------------------------------------------------------------------------
extern "C" void kernel_launch(void* const* d_in, const int* in_sizes, int n_in,
                              void* d_out, int out_size, void* d_ws, size_t ws_size,
                              hipStream_t stream) {
  const int*   node_kind    = (const int*)d_in[0];
  const int*   node_content = (const int*)d_in[1];
  const int*   edge_index   = (const int*)d_in[2];
  const int*   edge_type    = (const int*)d_in[3];
  const int*   edge_pos     = (const int*)d_in[4];
  const int*   batch_vec    = (const int*)d_in[5];
  const float* kind_emb     = (const float*)d_in[6];
  const float* inst2vec     = (const float*)d_in[7];
  const float* type_emb     = (const float*)d_in[8];
  const float* etype_emb    = (const float*)d_in[9];
  const float* epos_emb     = (const float*)d_in[10];
  const float* W1   = (const float*)d_in[11];
  const float* b1   = (const float*)d_in[12];
  const float* bn_g = (const float*)d_in[13];
  const float* bn_b = (const float*)d_in[14];
  const float* bn_m = (const float*)d_in[15];
  const float* bn_v = (const float*)d_in[16];
  const float* W2   = (const float*)d_in[17];
  const float* b2   = (const float*)d_in[18];
  const float* fcW  = (const float*)d_in[19];
  const float* fcb  = (const float*)d_in[20];
  float* out = (float*)d_out;

  char* ws = (char*)d_ws;
  float* x     = (float*)(ws + 0ull);           // 50000*200*4 = 40,000,000
  float* y     = (float*)(ws + 40000000ull);    // 40,000,000
  float* ecomb = (float*)(ws + 80000000ull);    // 60*200*4 = 48,000
  int*   deg   = (int*)  (ws + 80048000ull);    // 200,000
  int*   offs  = (int*)  (ws + 80248000ull);    // 200,016
  int*   cursor= (int*)  (ws + 80448016ull);    // 200,000
  int*   e_src = (int*)  (ws + 80648016ull);    // 1,600,000
  int*   e_code= (int*)  (ws + 82248016ull);    // 1,600,000
  int*   gstart= (int*)  (ws + 83848016ull);    // 272
  float* pools = (float*)(ws + 83848288ull);    // 6*64*200*4 = 307,200

  const int* src = edge_index;
  const int* dst = edge_index + N_EDGES;

  hipMemsetAsync(deg, 0, N_NODES * sizeof(int), stream);
  hipMemsetAsync(pools, 0, (NLAYERS + 1) * N_GRAPHS * HID * sizeof(float), stream);

  embed_kernel<<<N_NODES, 256, 0, stream>>>(node_kind, node_content, kind_emb, inst2vec, type_emb, x);
  ecomb_kernel<<<60, 256, 0, stream>>>(etype_emb, epos_emb, ecomb);
  hist_kernel<<<(N_EDGES + 255) / 256, 256, 0, stream>>>(dst, deg);
  scan_kernel<<<1, 1024, 0, stream>>>(deg, offs, cursor);
  scatter_kernel<<<(N_EDGES + 255) / 256, 256, 0, stream>>>(src, dst, edge_type, edge_pos,
                                                            cursor, e_src, e_code);
  gstart_kernel<<<1, 128, 0, stream>>>(batch_vec, gstart);

  int gblocks = (N_NODES + 127) / 128;
  for (int i = 0; i < NLAYERS; ++i) {
    pool_kernel<<<dim3(N_GRAPHS, 8), 256, 0, stream>>>(x, pools + (size_t)i * N_GRAPHS * HID, gstart);
    agg_kernel<<<N_NODES, 256, 0, stream>>>(x, y, offs, e_src, e_code, ecomb);
    gemm_kernel<1><<<gblocks, 256, 0, stream>>>(y, y, W1 + (size_t)i * HID * HID,
        b1 + i * HID, bn_m + i * HID, bn_g + i * HID, bn_v + i * HID, bn_b + i * HID);
    gemm_kernel<2><<<gblocks, 256, 0, stream>>>(y, x, W2 + (size_t)i * HID * HID,
        b2 + i * HID, nullptr, nullptr, nullptr, nullptr);
  }
  pool_kernel<<<dim3(N_GRAPHS, 8), 256, 0, stream>>>(x, pools + (size_t)NLAYERS * N_GRAPHS * HID, gstart);
  head_kernel<<<1, 1024, 0, stream>>>(pools, gstart, fcW, fcb, out);
}

// Round 2
// 914.522 us; speedup vs baseline: 2.7301x; 2.7301x over previous
//
#include <hip/hip_runtime.h>
#include <hip/hip_bf16.h>

#define N_NODES 50000
#define N_EDGES 400000
#define N_GRAPHS 64
#define HID 200
#define NUM_OUT 16
#define NLAYERS 5
#define CPAD 256            // padded channel count (K and N of GEMMs)
#define MPAD 50048          // padded row count (multiple of 128)

typedef unsigned short ushort_t;
typedef short short8 __attribute__((ext_vector_type(8)));
typedef float f32x4 __attribute__((ext_vector_type(4)));

__device__ __forceinline__ float b2f(ushort_t u) {
  return __uint_as_float(((unsigned)u) << 16);
}
__device__ __forceinline__ ushort_t f2b(float f) {
  unsigned u = __float_as_uint(f);
  unsigned r = (u + 0x7FFFu + ((u >> 16) & 1u)) >> 16;
  return (ushort_t)r;
}

__device__ __forceinline__ void gload_lds16(const void* g, void* l) {
  __builtin_amdgcn_global_load_lds(
      (const __attribute__((address_space(1))) unsigned int*)g,
      (__attribute__((address_space(3))) unsigned int*)l, 16, 0, 0);
}

// ---------------------------------------------------------------------------
// node embedding -> bf16 padded [MPAD][256]; pad rows/channels = 0
__global__ void embed_kernel(const int* __restrict__ kind, const int* __restrict__ content,
                             const float* __restrict__ kind_emb, const float* __restrict__ inst2vec,
                             const float* __restrict__ type_emb, ushort_t* __restrict__ x) {
  long n = blockIdx.x; int ch = threadIdx.x;
  ushort_t v = 0;
  if (n < N_NODES && ch < HID) {
    int k = kind[n];
    float f = kind_emb[k * HID + ch];
    f += (k == 0) ? inst2vec[(size_t)content[n] * HID + ch] : type_emb[ch];
    v = f2b(f);
  }
  x[n * CPAD + ch] = v;
}

// edge-embedding table fp32 padded [60][256], pad = 0
__global__ void ecomb_kernel(const float* __restrict__ etype_emb, const float* __restrict__ epos_emb,
                             float* __restrict__ ecomb) {
  int code = blockIdx.x; int ch = threadIdx.x;
  float v = 0.f;
  if (ch < HID) v = etype_emb[(code / 20) * HID + ch] + epos_emb[(code % 20) * HID + ch];
  ecomb[code * CPAD + ch] = v;
}

// weights: bf16, transposed, padded.  Wt[g][n][k], g=2i -> W1[i], g=2i+1 -> W2[i]
__global__ void prep_w(const float* __restrict__ W1, const float* __restrict__ W2,
                       ushort_t* __restrict__ Wt) {
  int idx = blockIdx.x * 256 + threadIdx.x;   // 10*256*256 total
  int g = idx >> 16; int rem = idx & 65535; int n = rem >> 8; int k = rem & 255;
  float v = 0.f;
  if (n < HID && k < HID) {
    int i = g >> 1;
    v = (g & 1) ? W2[(size_t)i * HID * HID + (size_t)k * HID + n]
                : W1[(size_t)i * HID * HID + (size_t)k * HID + n];
  }
  Wt[idx] = f2b(v);
}

// epilogue tables: out = relu(acc*s + t); pad channels s=t=0 (keeps pads zero)
__global__ void prep_st(const float* __restrict__ b1, const float* __restrict__ bn_g,
                        const float* __restrict__ bn_b, const float* __restrict__ bn_m,
                        const float* __restrict__ bn_v, const float* __restrict__ b2,
                        float2* __restrict__ ST) {
  int idx = blockIdx.x * 256 + threadIdx.x;   // 10*256
  int g = idx >> 8, c = idx & 255;
  float s = 0.f, t = 0.f;
  if (c < HID) {
    int i = g >> 1;
    if (g & 1) { s = 1.f; t = b2[i * HID + c]; }
    else {
      float sc = bn_g[i * HID + c] * rsqrtf(bn_v[i * HID + c] + 1e-5f);
      s = sc; t = (b1[i * HID + c] - bn_m[i * HID + c]) * sc + bn_b[i * HID + c];
    }
  }
  ST[idx] = make_float2(s, t);
}

// CSR build
__global__ void hist_kernel(const int* __restrict__ dst, int* __restrict__ deg) {
  int e = blockIdx.x * 256 + threadIdx.x;
  if (e < N_EDGES) atomicAdd(&deg[dst[e]], 1);
}

__global__ void scan_kernel(const int* __restrict__ deg, int* __restrict__ offs, int* __restrict__ cursor) {
  __shared__ int buf[1024];
  __shared__ int carry_s;
  int tid = threadIdx.x;
  if (tid == 0) carry_s = 0;
  __syncthreads();
  for (int base = 0; base < N_NODES; base += 1024) {
    int i = base + tid;
    int v = (i < N_NODES) ? deg[i] : 0;
    buf[tid] = v;
    __syncthreads();
    for (int off = 1; off < 1024; off <<= 1) {
      int t = (tid >= off) ? buf[tid - off] : 0;
      __syncthreads();
      buf[tid] += t;
      __syncthreads();
    }
    int incl = buf[tid];
    int carry = carry_s;
    if (i < N_NODES) { int excl = carry + incl - v; offs[i] = excl; cursor[i] = excl; }
    __syncthreads();
    if (tid == 1023) carry_s = carry + incl;
    __syncthreads();
  }
  if (tid == 0) offs[N_NODES] = carry_s;
}

__global__ void scatter_kernel(const int* __restrict__ src, const int* __restrict__ dst,
                               const int* __restrict__ etype, const int* __restrict__ epos,
                               int* __restrict__ cursor, int* __restrict__ e_src, int* __restrict__ e_code) {
  int e = blockIdx.x * 256 + threadIdx.x;
  if (e >= N_EDGES) return;
  int d = dst[e];
  int slot = atomicAdd(&cursor[d], 1);
  e_src[slot] = src[e];
  int p = epos[e]; if (p > 19) p = 19;
  e_code[slot] = etype[e] * 20 + p;
}

__global__ void gstart_kernel(const int* __restrict__ bv, int* __restrict__ gstart) {
  int g = threadIdx.x;
  if (g > N_GRAPHS) return;
  if (g == N_GRAPHS) { gstart[N_GRAPHS] = N_NODES; return; }
  int lo = 0, hi = N_NODES;
  while (lo < hi) { int mid = (lo + hi) >> 1; if (bv[mid] < g) lo = mid + 1; else hi = mid; }
  gstart[g] = lo;
}

// GINE aggregation in bf16: one wave per node; lane covers 4 channels
__global__ void agg_kernel(const ushort_t* __restrict__ x, ushort_t* __restrict__ y,
                           const int* __restrict__ offs, const int* __restrict__ e_src,
                           const int* __restrict__ e_code, const float* __restrict__ ecomb) {
  int w = threadIdx.x >> 6;
  int lane = threadIdx.x & 63;
  int n = blockIdx.x * 4 + w;
  if (n >= N_NODES) return;
  int s0 = offs[n], s1 = offs[n + 1];
  const ushort4* xv = (const ushort4*)x;
  float a0 = 0.f, a1 = 0.f, a2 = 0.f, a3 = 0.f;
  for (int j = s0; j < s1; ++j) {
    int s = e_src[j], code = e_code[j];
    ushort4 xs = xv[(size_t)s * 64 + lane];
    float4 ec = *(const float4*)(ecomb + (size_t)code * CPAD + lane * 4);
    a0 += fmaxf(b2f(xs.x) + ec.x, 0.f);
    a1 += fmaxf(b2f(xs.y) + ec.y, 0.f);
    a2 += fmaxf(b2f(xs.z) + ec.z, 0.f);
    a3 += fmaxf(b2f(xs.w) + ec.w, 0.f);
  }
  ushort4 xn = xv[(size_t)n * 64 + lane];
  ushort4 o;
  o.x = f2b(b2f(xn.x) + a0);
  o.y = f2b(b2f(xn.y) + a1);
  o.z = f2b(b2f(xn.z) + a2);
  o.w = f2b(b2f(xn.w) + a3);
  ((ushort4*)y)[(size_t)n * 64 + lane] = o;
}

// ---------------------------------------------------------------------------
// bf16 MFMA GEMM: C[MPAD x 256] = A[MPAD x 256] @ W[256 x 256] (W given transposed),
// epilogue relu(acc*s + t) per column, bf16 out.  BM=128, BN=256, BK=64, 8 waves.
__global__ __launch_bounds__(512, 4) void mfma_gemm(
    const ushort_t* __restrict__ A, ushort_t* __restrict__ C,
    const ushort_t* __restrict__ Wt, const float2* __restrict__ ST) {
  __shared__ char lds[48 * 1024];       // A: 0..16K, B: 16K..48K
  char* A_l = lds;
  char* B_l = lds + 16384;
  const int tid = threadIdx.x;
  const int lane = tid & 63, wid = tid >> 6;
  const int wm = wid >> 2, wn = wid & 3;
  const size_t r0 = (size_t)blockIdx.x * 128;

  f32x4 acc[4][4];
  #pragma unroll
  for (int mi = 0; mi < 4; mi++)
    #pragma unroll
    for (int ni = 0; ni < 4; ni++) acc[mi][ni] = (f32x4){0.f, 0.f, 0.f, 0.f};

  const char* Ab = (const char*)A;
  const char* Wb = (const char*)Wt;

  for (int k0 = 0; k0 < CPAD; k0 += 64) {
    __syncthreads();
    // stage A tile [128 rows][64 k] bf16, XOR-swizzled via pre-swizzled global src
    #pragma unroll
    for (int c = 0; c < 2; c++) {
      int d = tid * 16 + c * 8192;
      int rowd = d >> 7;
      int slot = (d >> 4) & 7;
      int lslot = slot ^ (rowd & 7);
      gload_lds16(Ab + (r0 + rowd) * 512 + k0 * 2 + lslot * 16, A_l + d);
    }
    // stage Wt tile [256 n][64 k]
    #pragma unroll
    for (int c = 0; c < 4; c++) {
      int d = tid * 16 + c * 8192;
      int rowd = d >> 7;
      int slot = (d >> 4) & 7;
      int lslot = slot ^ (rowd & 7);
      gload_lds16(Wb + (size_t)rowd * 512 + k0 * 2 + lslot * 16, B_l + d);
    }
    __syncthreads();
    #pragma unroll
    for (int s = 0; s < 2; s++) {
      short8 bfr[4];
      #pragma unroll
      for (int ni = 0; ni < 4; ni++) {
        int brow = wn * 64 + ni * 16 + (lane & 15);
        int off = brow * 128 + (((s * 4 + (lane >> 4)) ^ (lane & 7)) << 4);
        bfr[ni] = *(const short8*)(B_l + off);
      }
      #pragma unroll
      for (int mi = 0; mi < 4; mi++) {
        int arow = wm * 64 + mi * 16 + (lane & 15);
        int off = arow * 128 + (((s * 4 + (lane >> 4)) ^ (lane & 7)) << 4);
        short8 af = *(const short8*)(A_l + off);
        #pragma unroll
        for (int ni = 0; ni < 4; ni++)
          acc[mi][ni] = __builtin_amdgcn_mfma_f32_16x16x32_bf16(af, bfr[ni], acc[mi][ni], 0, 0, 0);
      }
    }
  }

  // epilogue: relu(acc*s + t) -> bf16
  #pragma unroll
  for (int ni = 0; ni < 4; ni++) {
    int col = wn * 64 + ni * 16 + (lane & 15);
    float2 st = ST[col];
    #pragma unroll
    for (int mi = 0; mi < 4; mi++) {
      int rbase = wm * 64 + mi * 16 + (lane >> 4) * 4;
      #pragma unroll
      for (int j = 0; j < 4; j++) {
        float v = fmaf(acc[mi][ni][j], st.x, st.y);
        v = fmaxf(v, 0.f);
        C[(r0 + rbase + j) * CPAD + col] = f2b(v);
      }
    }
  }
}

// per-graph partial sums (fp32 accum over bf16 x)
__global__ void pool_kernel(const ushort_t* __restrict__ x, float* __restrict__ pool_sum,
                            const int* __restrict__ gstart) {
  int g = blockIdx.x, chunk = blockIdx.y, ch = threadIdx.x;
  if (ch >= HID) return;
  int s = gstart[g], e = gstart[g + 1];
  int len = e - s;
  int per = (len + (int)gridDim.y - 1) / (int)gridDim.y;
  int cs = s + chunk * per; int ce = cs + per; if (ce > e) ce = e;
  if (cs >= ce) return;
  float acc = 0.f;
  for (int n = cs; n < ce; ++n) acc += b2f(x[(size_t)n * CPAD + ch]);
  atomicAdd(&pool_sum[g * HID + ch], acc);
}

__global__ void head_kernel(const float* __restrict__ pools, const int* __restrict__ gstart,
                            const float* __restrict__ fcW, const float* __restrict__ fcb,
                            float* __restrict__ out) {
  int tid = threadIdx.x;
  if (tid >= N_GRAPHS * NUM_OUT) return;
  int g = tid >> 4, o = tid & 15;
  int cnt = gstart[g + 1] - gstart[g];
  float inv = 1.f / (float)(cnt > 0 ? cnt : 1);
  float acc = 0.f;
  for (int i = 0; i < NLAYERS + 1; ++i) {
    const float* ps = pools + (size_t)(i * N_GRAPHS + g) * HID;
    const float* w = fcW + (size_t)(i * HID) * NUM_OUT + o;
    float a = 0.f;
    for (int c = 0; c < HID; ++c) a = fmaf(ps[c], w[c * NUM_OUT], a);
    acc += a * inv + fcb[i * NUM_OUT + o];
  }
  out[g * NUM_OUT + o] = acc;
}

// ---------------------------------------------------------------------------
extern "C" void kernel_launch(void* const* d_in, const int* in_sizes, int n_in,
                              void* d_out, int out_size, void* d_ws, size_t ws_size,
                              hipStream_t stream) {
  const int*   node_kind    = (const int*)d_in[0];
  const int*   node_content = (const int*)d_in[1];
  const int*   edge_index   = (const int*)d_in[2];
  const int*   edge_type    = (const int*)d_in[3];
  const int*   edge_pos     = (const int*)d_in[4];
  const int*   batch_vec    = (const int*)d_in[5];
  const float* kind_emb     = (const float*)d_in[6];
  const float* inst2vec     = (const float*)d_in[7];
  const float* type_emb     = (const float*)d_in[8];
  const float* etype_emb    = (const float*)d_in[9];
  const float* epos_emb     = (const float*)d_in[10];
  const float* W1   = (const float*)d_in[11];
  const float* b1   = (const float*)d_in[12];
  const float* bn_g = (const float*)d_in[13];
  const float* bn_b = (const float*)d_in[14];
  const float* bn_m = (const float*)d_in[15];
  const float* bn_v = (const float*)d_in[16];
  const float* W2   = (const float*)d_in[17];
  const float* b2   = (const float*)d_in[18];
  const float* fcW  = (const float*)d_in[19];
  const float* fcb  = (const float*)d_in[20];
  float* out = (float*)d_out;

  char* ws = (char*)d_ws;
  ushort_t* x     = (ushort_t*)(ws + 0ull);           // MPAD*256*2 = 25,624,576
  ushort_t* y     = (ushort_t*)(ws + 25624576ull);    // 25,624,576
  ushort_t* Wt    = (ushort_t*)(ws + 51249152ull);    // 10*256*256*2 = 1,310,720
  float2*   ST    = (float2*)  (ws + 52559872ull);    // 10*256*8 = 20,480
  float*    ecomb = (float*)   (ws + 52580352ull);    // 60*256*4 = 61,440
  int*      deg   = (int*)     (ws + 52641792ull);    // 200,000
  int*      offs  = (int*)     (ws + 52841792ull);    // 200,016
  int*      cursor= (int*)     (ws + 53041824ull);    // 200,000
  int*      e_src = (int*)     (ws + 53241824ull);    // 1,600,000
  int*      e_code= (int*)     (ws + 54841824ull);    // 1,600,000
  int*      gstart= (int*)     (ws + 56441824ull);    // 260
  float*    pools = (float*)   (ws + 56442096ull);    // 6*64*200*4 = 307,200

  const int* srcp = edge_index;
  const int* dstp = edge_index + N_EDGES;

  hipMemsetAsync(deg, 0, N_NODES * sizeof(int), stream);
  hipMemsetAsync(pools, 0, (NLAYERS + 1) * N_GRAPHS * HID * sizeof(float), stream);
  // zero pad rows of y once per launch (agg does not write them)
  hipMemsetAsync(y + (size_t)N_NODES * CPAD, 0, (size_t)(MPAD - N_NODES) * CPAD * 2, stream);

  prep_w<<<(10 * 256 * 256) / 256, 256, 0, stream>>>(W1, W2, Wt);
  prep_st<<<10, 256, 0, stream>>>(b1, bn_g, bn_b, bn_m, bn_v, b2, ST);
  ecomb_kernel<<<60, 256, 0, stream>>>(etype_emb, epos_emb, ecomb);
  embed_kernel<<<MPAD, 256, 0, stream>>>(node_kind, node_content, kind_emb, inst2vec, type_emb, x);
  hist_kernel<<<(N_EDGES + 255) / 256, 256, 0, stream>>>(dstp, deg);
  scan_kernel<<<1, 1024, 0, stream>>>(deg, offs, cursor);
  scatter_kernel<<<(N_EDGES + 255) / 256, 256, 0, stream>>>(srcp, dstp, edge_type, edge_pos,
                                                            cursor, e_src, e_code);
  gstart_kernel<<<1, 128, 0, stream>>>(batch_vec, gstart);

  const int gblocks = MPAD / 128;   // 391
  for (int i = 0; i < NLAYERS; ++i) {
    pool_kernel<<<dim3(N_GRAPHS, 8), 256, 0, stream>>>(x, pools + (size_t)i * N_GRAPHS * HID, gstart);
    agg_kernel<<<(N_NODES + 3) / 4, 256, 0, stream>>>(x, y, offs, e_src, e_code, ecomb);
    mfma_gemm<<<gblocks, 512, 0, stream>>>(y, y, Wt + (size_t)(2 * i) * 65536, ST + (size_t)(2 * i) * 256);
    mfma_gemm<<<gblocks, 512, 0, stream>>>(y, x, Wt + (size_t)(2 * i + 1) * 65536, ST + (size_t)(2 * i + 1) * 256);
  }
  pool_kernel<<<dim3(N_GRAPHS, 8), 256, 0, stream>>>(x, pools + (size_t)NLAYERS * N_GRAPHS * HID, gstart);
  head_kernel<<<1, 1024, 0, stream>>>(pools, gstart, fcW, fcb, out);
}

// Round 3
// 720.135 us; speedup vs baseline: 3.4670x; 1.2699x over previous
//
#include <hip/hip_runtime.h>
#include <hip/hip_bf16.h>

#define N_NODES 50000
#define N_EDGES 400000
#define N_GRAPHS 64
#define HID 200
#define NUM_OUT 16
#define NLAYERS 5
#define CPAD 256            // padded channel count (K and N of GEMMs)
#define MPAD 50048          // padded row count (multiple of 128)
#define SCAN_B 196          // ceil(N_NODES/256)

typedef unsigned short ushort_t;
typedef short short8 __attribute__((ext_vector_type(8)));
typedef float f32x4 __attribute__((ext_vector_type(4)));

__device__ __forceinline__ float b2f(ushort_t u) {
  return __uint_as_float(((unsigned)u) << 16);
}
__device__ __forceinline__ ushort_t f2b(float f) {
  unsigned u = __float_as_uint(f);
  unsigned r = (u + 0x7FFFu + ((u >> 16) & 1u)) >> 16;
  return (ushort_t)r;
}

__device__ __forceinline__ void gload_lds16(const void* g, void* l) {
  __builtin_amdgcn_global_load_lds(
      (const __attribute__((address_space(1))) unsigned int*)g,
      (__attribute__((address_space(3))) unsigned int*)l, 16, 0, 0);
}

// ---------------------------------------------------------------------------
// node embedding -> bf16 padded [MPAD][256]; pad rows/channels = 0
__global__ void embed_kernel(const int* __restrict__ kind, const int* __restrict__ content,
                             const float* __restrict__ kind_emb, const float* __restrict__ inst2vec,
                             const float* __restrict__ type_emb, ushort_t* __restrict__ x) {
  long n = blockIdx.x; int ch = threadIdx.x;
  ushort_t v = 0;
  if (n < N_NODES && ch < HID) {
    int k = kind[n];
    float f = kind_emb[k * HID + ch];
    f += (k == 0) ? inst2vec[(size_t)content[n] * HID + ch] : type_emb[ch];
    v = f2b(f);
  }
  x[n * CPAD + ch] = v;
}

// edge-embedding table fp32 padded [60][256], pad = 0
__global__ void ecomb_kernel(const float* __restrict__ etype_emb, const float* __restrict__ epos_emb,
                             float* __restrict__ ecomb) {
  int code = blockIdx.x; int ch = threadIdx.x;
  float v = 0.f;
  if (ch < HID) v = etype_emb[(code / 20) * HID + ch] + epos_emb[(code % 20) * HID + ch];
  ecomb[code * CPAD + ch] = v;
}

// weights: bf16, transposed, padded.  Wt[g][n][k], g=2i -> W1[i], g=2i+1 -> W2[i]
__global__ void prep_w(const float* __restrict__ W1, const float* __restrict__ W2,
                       ushort_t* __restrict__ Wt) {
  int idx = blockIdx.x * 256 + threadIdx.x;   // 10*256*256 total
  int g = idx >> 16; int rem = idx & 65535; int n = rem >> 8; int k = rem & 255;
  float v = 0.f;
  if (n < HID && k < HID) {
    int i = g >> 1;
    v = (g & 1) ? W2[(size_t)i * HID * HID + (size_t)k * HID + n]
                : W1[(size_t)i * HID * HID + (size_t)k * HID + n];
  }
  Wt[idx] = f2b(v);
}

// epilogue tables: out = relu(acc*s + t); pad channels s=t=0 (keeps pads zero)
__global__ void prep_st(const float* __restrict__ b1, const float* __restrict__ bn_g,
                        const float* __restrict__ bn_b, const float* __restrict__ bn_m,
                        const float* __restrict__ bn_v, const float* __restrict__ b2,
                        float2* __restrict__ ST) {
  int idx = blockIdx.x * 256 + threadIdx.x;   // 10*256
  int g = idx >> 8, c = idx & 255;
  float s = 0.f, t = 0.f;
  if (c < HID) {
    int i = g >> 1;
    if (g & 1) { s = 1.f; t = b2[i * HID + c]; }
    else {
      float sc = bn_g[i * HID + c] * rsqrtf(bn_v[i * HID + c] + 1e-5f);
      s = sc; t = (b1[i * HID + c] - bn_m[i * HID + c]) * sc + bn_b[i * HID + c];
    }
  }
  ST[idx] = make_float2(s, t);
}

// CSR build
__global__ void hist_kernel(const int* __restrict__ dst, int* __restrict__ deg) {
  int e = blockIdx.x * 256 + threadIdx.x;
  if (e < N_EDGES) atomicAdd(&deg[dst[e]], 1);
}

// hierarchical scan: (1) per-block reduce, (2) scan block sums, (3) local scan + add
__global__ void scan1_kernel(const int* __restrict__ deg, int* __restrict__ bsum) {
  __shared__ int red[256];
  int b = blockIdx.x, t = threadIdx.x;
  int i = b * 256 + t;
  red[t] = (i < N_NODES) ? deg[i] : 0;
  __syncthreads();
  for (int off = 128; off > 0; off >>= 1) {
    if (t < off) red[t] += red[t + off];
    __syncthreads();
  }
  if (t == 0) bsum[b] = red[0];
}

__global__ void scan2_kernel(const int* __restrict__ bsum, int* __restrict__ bpre,
                             int* __restrict__ offs) {
  __shared__ int buf[256];
  int t = threadIdx.x;
  int v = (t < SCAN_B) ? bsum[t] : 0;
  buf[t] = v;
  __syncthreads();
  for (int off = 1; off < 256; off <<= 1) {
    int tv = (t >= off) ? buf[t - off] : 0;
    __syncthreads();
    buf[t] += tv;
    __syncthreads();
  }
  if (t < SCAN_B) bpre[t] = buf[t] - v;
  if (t == 255) offs[N_NODES] = buf[255];
}

__global__ void scan3_kernel(const int* __restrict__ deg, const int* __restrict__ bpre,
                             int* __restrict__ offs, int* __restrict__ cursor) {
  __shared__ int buf[256];
  int b = blockIdx.x, t = threadIdx.x;
  int i = b * 256 + t;
  int v = (i < N_NODES) ? deg[i] : 0;
  buf[t] = v;
  __syncthreads();
  for (int off = 1; off < 256; off <<= 1) {
    int tv = (t >= off) ? buf[t - off] : 0;
    __syncthreads();
    buf[t] += tv;
    __syncthreads();
  }
  if (i < N_NODES) {
    int e = bpre[b] + buf[t] - v;
    offs[i] = e; cursor[i] = e;
  }
}

__global__ void scatter_kernel(const int* __restrict__ src, const int* __restrict__ dst,
                               const int* __restrict__ etype, const int* __restrict__ epos,
                               int* __restrict__ cursor, int* __restrict__ e_src, int* __restrict__ e_code) {
  int e = blockIdx.x * 256 + threadIdx.x;
  if (e >= N_EDGES) return;
  int d = dst[e];
  int slot = atomicAdd(&cursor[d], 1);
  e_src[slot] = src[e];
  int p = epos[e]; if (p > 19) p = 19;
  e_code[slot] = etype[e] * 20 + p;
}

__global__ void gstart_kernel(const int* __restrict__ bv, int* __restrict__ gstart) {
  int g = threadIdx.x;
  if (g > N_GRAPHS) return;
  if (g == N_GRAPHS) { gstart[N_GRAPHS] = N_NODES; return; }
  int lo = 0, hi = N_NODES;
  while (lo < hi) { int mid = (lo + hi) >> 1; if (bv[mid] < g) lo = mid + 1; else hi = mid; }
  gstart[g] = lo;
}

// GINE aggregation in bf16: one wave per node; lane covers 4 channels
__global__ void agg_kernel(const ushort_t* __restrict__ x, ushort_t* __restrict__ y,
                           const int* __restrict__ offs, const int* __restrict__ e_src,
                           const int* __restrict__ e_code, const float* __restrict__ ecomb) {
  int w = threadIdx.x >> 6;
  int lane = threadIdx.x & 63;
  int n = blockIdx.x * 4 + w;
  if (n >= N_NODES) return;
  int s0 = offs[n], s1 = offs[n + 1];
  const ushort4* xv = (const ushort4*)x;
  float a0 = 0.f, a1 = 0.f, a2 = 0.f, a3 = 0.f;
  for (int j = s0; j < s1; ++j) {
    int s = e_src[j], code = e_code[j];
    ushort4 xs = xv[(size_t)s * 64 + lane];
    float4 ec = *(const float4*)(ecomb + (size_t)code * CPAD + lane * 4);
    a0 += fmaxf(b2f(xs.x) + ec.x, 0.f);
    a1 += fmaxf(b2f(xs.y) + ec.y, 0.f);
    a2 += fmaxf(b2f(xs.z) + ec.z, 0.f);
    a3 += fmaxf(b2f(xs.w) + ec.w, 0.f);
  }
  ushort4 xn = xv[(size_t)n * 64 + lane];
  ushort4 o;
  o.x = f2b(b2f(xn.x) + a0);
  o.y = f2b(b2f(xn.y) + a1);
  o.z = f2b(b2f(xn.z) + a2);
  o.w = f2b(b2f(xn.w) + a3);
  ((ushort4*)y)[(size_t)n * 64 + lane] = o;
}

// ---------------------------------------------------------------------------
// bf16 MFMA GEMM: C[MPAD x 256] = A[MPAD x 256] @ W (given transposed [256 n][256 k]),
// epilogue relu(acc*s + t) per column, bf16 out.
// BM=128, BN=256, BK=64; 4 waves, wave tile 64x128 (acc[4][8]) for lower LDS traffic.
__global__ __launch_bounds__(256, 2) void mfma_gemm(
    const ushort_t* __restrict__ A, ushort_t* __restrict__ C,
    const ushort_t* __restrict__ Wt, const float2* __restrict__ ST) {
  __shared__ char lds[48 * 1024];       // A: 0..16K (128 rows x 128B), B: 16K..48K (256 rows x 128B)
  char* A_l = lds;
  char* B_l = lds + 16384;
  const int tid = threadIdx.x;
  const int lane = tid & 63, wid = tid >> 6;
  const int wm = wid >> 1, wn = wid & 1;
  const size_t r0 = (size_t)blockIdx.x * 128;

  f32x4 acc[4][8];
  #pragma unroll
  for (int mi = 0; mi < 4; mi++)
    #pragma unroll
    for (int ni = 0; ni < 8; ni++) acc[mi][ni] = (f32x4){0.f, 0.f, 0.f, 0.f};

  const char* Ab = (const char*)A;
  const char* Wb = (const char*)Wt;

  for (int k0 = 0; k0 < CPAD; k0 += 64) {
    __syncthreads();   // protect previous iteration's LDS reads
    // stage A tile [128 rows][64 k] bf16, XOR-swizzled via pre-swizzled global src
    #pragma unroll
    for (int c = 0; c < 4; c++) {
      int d = tid * 16 + c * 4096;
      int rowd = d >> 7;
      int slot = (d >> 4) & 7;
      int lslot = slot ^ (rowd & 7);
      gload_lds16(Ab + (r0 + rowd) * 512 + k0 * 2 + lslot * 16, A_l + d);
    }
    // stage Wt tile [256 n][64 k]
    #pragma unroll
    for (int c = 0; c < 8; c++) {
      int d = tid * 16 + c * 4096;
      int rowd = d >> 7;
      int slot = (d >> 4) & 7;
      int lslot = slot ^ (rowd & 7);
      gload_lds16(Wb + (size_t)rowd * 512 + k0 * 2 + lslot * 16, B_l + d);
    }
    __syncthreads();
    #pragma unroll
    for (int s = 0; s < 2; s++) {
      short8 bfr[8];
      #pragma unroll
      for (int ni = 0; ni < 8; ni++) {
        int brow = wn * 128 + ni * 16 + (lane & 15);
        int off = brow * 128 + (((s * 4 + (lane >> 4)) ^ (brow & 7)) << 4);
        bfr[ni] = *(const short8*)(B_l + off);
      }
      #pragma unroll
      for (int mi = 0; mi < 4; mi++) {
        int arow = wm * 64 + mi * 16 + (lane & 15);
        int off = arow * 128 + (((s * 4 + (lane >> 4)) ^ (arow & 7)) << 4);
        short8 af = *(const short8*)(A_l + off);
        #pragma unroll
        for (int ni = 0; ni < 8; ni++)
          acc[mi][ni] = __builtin_amdgcn_mfma_f32_16x16x32_bf16(af, bfr[ni], acc[mi][ni], 0, 0, 0);
      }
    }
  }

  // epilogue: relu(acc*s + t) -> bf16
  #pragma unroll
  for (int ni = 0; ni < 8; ni++) {
    int col = wn * 128 + ni * 16 + (lane & 15);
    float2 st = ST[col];
    #pragma unroll
    for (int mi = 0; mi < 4; mi++) {
      int rbase = wm * 64 + mi * 16 + (lane >> 4) * 4;
      #pragma unroll
      for (int j = 0; j < 4; j++) {
        float v = fmaf(acc[mi][ni][j], st.x, st.y);
        v = fmaxf(v, 0.f);
        C[(r0 + rbase + j) * CPAD + col] = f2b(v);
      }
    }
  }
}

// per-graph partial sums: wave per row-stripe, ushort4/lane, register accum, 4 atomics/lane
__global__ void pool_kernel(const ushort_t* __restrict__ x, float* __restrict__ pool_sum,
                            const int* __restrict__ gstart) {
  int g = blockIdx.x, chunk = blockIdx.y;
  int w = threadIdx.x >> 6, lane = threadIdx.x & 63;
  int s = gstart[g], e = gstart[g + 1];
  int len = e - s;
  int per = (len + (int)gridDim.y - 1) / (int)gridDim.y;
  int cs = s + chunk * per; int ce = cs + per; if (ce > e) ce = e;
  if (cs >= ce) return;
  const ushort4* xv = (const ushort4*)x;
  float a0 = 0.f, a1 = 0.f, a2 = 0.f, a3 = 0.f;
  for (int n = cs + w; n < ce; n += 4) {
    ushort4 t = xv[(size_t)n * 64 + lane];
    a0 += b2f(t.x); a1 += b2f(t.y); a2 += b2f(t.z); a3 += b2f(t.w);
  }
  int c = lane * 4;
  if (c < HID) {   // HID=200 -> lanes 0..49 all have c..c+3 < 200
    atomicAdd(&pool_sum[g * HID + c + 0], a0);
    atomicAdd(&pool_sum[g * HID + c + 1], a1);
    atomicAdd(&pool_sum[g * HID + c + 2], a2);
    atomicAdd(&pool_sum[g * HID + c + 3], a3);
  }
}

__global__ void head_kernel(const float* __restrict__ pools, const int* __restrict__ gstart,
                            const float* __restrict__ fcW, const float* __restrict__ fcb,
                            float* __restrict__ out) {
  int tid = threadIdx.x;
  if (tid >= N_GRAPHS * NUM_OUT) return;
  int g = tid >> 4, o = tid & 15;
  int cnt = gstart[g + 1] - gstart[g];
  float inv = 1.f / (float)(cnt > 0 ? cnt : 1);
  float acc = 0.f;
  for (int i = 0; i < NLAYERS + 1; ++i) {
    const float* ps = pools + (size_t)(i * N_GRAPHS + g) * HID;
    const float* w = fcW + (size_t)(i * HID) * NUM_OUT + o;
    float a = 0.f;
    for (int c = 0; c < HID; ++c) a = fmaf(ps[c], w[c * NUM_OUT], a);
    acc += a * inv + fcb[i * NUM_OUT + o];
  }
  out[g * NUM_OUT + o] = acc;
}

// ---------------------------------------------------------------------------
extern "C" void kernel_launch(void* const* d_in, const int* in_sizes, int n_in,
                              void* d_out, int out_size, void* d_ws, size_t ws_size,
                              hipStream_t stream) {
  const int*   node_kind    = (const int*)d_in[0];
  const int*   node_content = (const int*)d_in[1];
  const int*   edge_index   = (const int*)d_in[2];
  const int*   edge_type    = (const int*)d_in[3];
  const int*   edge_pos     = (const int*)d_in[4];
  const int*   batch_vec    = (const int*)d_in[5];
  const float* kind_emb     = (const float*)d_in[6];
  const float* inst2vec     = (const float*)d_in[7];
  const float* type_emb     = (const float*)d_in[8];
  const float* etype_emb    = (const float*)d_in[9];
  const float* epos_emb     = (const float*)d_in[10];
  const float* W1   = (const float*)d_in[11];
  const float* b1   = (const float*)d_in[12];
  const float* bn_g = (const float*)d_in[13];
  const float* bn_b = (const float*)d_in[14];
  const float* bn_m = (const float*)d_in[15];
  const float* bn_v = (const float*)d_in[16];
  const float* W2   = (const float*)d_in[17];
  const float* b2   = (const float*)d_in[18];
  const float* fcW  = (const float*)d_in[19];
  const float* fcb  = (const float*)d_in[20];
  float* out = (float*)d_out;

  char* ws = (char*)d_ws;
  ushort_t* x     = (ushort_t*)(ws + 0ull);           // MPAD*256*2 = 25,624,576
  ushort_t* y     = (ushort_t*)(ws + 25624576ull);    // 25,624,576
  ushort_t* Wt    = (ushort_t*)(ws + 51249152ull);    // 10*256*256*2 = 1,310,720
  float2*   ST    = (float2*)  (ws + 52559872ull);    // 10*256*8 = 20,480
  float*    ecomb = (float*)   (ws + 52580352ull);    // 60*256*4 = 61,440
  int*      deg   = (int*)     (ws + 52641792ull);    // 200,000
  int*      offs  = (int*)     (ws + 52841792ull);    // 200,016
  int*      cursor= (int*)     (ws + 53041824ull);    // 200,000
  int*      e_src = (int*)     (ws + 53241824ull);    // 1,600,000
  int*      e_code= (int*)     (ws + 54841824ull);    // 1,600,000
  int*      gstart= (int*)     (ws + 56441824ull);    // 260
  float*    pools = (float*)   (ws + 56442096ull);    // 6*64*200*4 = 307,200
  int*      bsum  = (int*)     (ws + 56749296ull);    // 784
  int*      bpre  = (int*)     (ws + 56750080ull);    // 784

  const int* srcp = edge_index;
  const int* dstp = edge_index + N_EDGES;

  hipMemsetAsync(deg, 0, N_NODES * sizeof(int), stream);
  hipMemsetAsync(pools, 0, (NLAYERS + 1) * N_GRAPHS * HID * sizeof(float), stream);
  // zero pad rows of y once per launch (agg does not write them)
  hipMemsetAsync(y + (size_t)N_NODES * CPAD, 0, (size_t)(MPAD - N_NODES) * CPAD * 2, stream);

  prep_w<<<(10 * 256 * 256) / 256, 256, 0, stream>>>(W1, W2, Wt);
  prep_st<<<10, 256, 0, stream>>>(b1, bn_g, bn_b, bn_m, bn_v, b2, ST);
  ecomb_kernel<<<60, 256, 0, stream>>>(etype_emb, epos_emb, ecomb);
  embed_kernel<<<MPAD, 256, 0, stream>>>(node_kind, node_content, kind_emb, inst2vec, type_emb, x);
  hist_kernel<<<(N_EDGES + 255) / 256, 256, 0, stream>>>(dstp, deg);
  scan1_kernel<<<SCAN_B, 256, 0, stream>>>(deg, bsum);
  scan2_kernel<<<1, 256, 0, stream>>>(bsum, bpre, offs);
  scan3_kernel<<<SCAN_B, 256, 0, stream>>>(deg, bpre, offs, cursor);
  scatter_kernel<<<(N_EDGES + 255) / 256, 256, 0, stream>>>(srcp, dstp, edge_type, edge_pos,
                                                            cursor, e_src, e_code);
  gstart_kernel<<<1, 128, 0, stream>>>(batch_vec, gstart);

  const int gblocks = MPAD / 128;   // 391
  for (int i = 0; i < NLAYERS; ++i) {
    pool_kernel<<<dim3(N_GRAPHS, 8), 256, 0, stream>>>(x, pools + (size_t)i * N_GRAPHS * HID, gstart);
    agg_kernel<<<(N_NODES + 3) / 4, 256, 0, stream>>>(x, y, offs, e_src, e_code, ecomb);
    mfma_gemm<<<gblocks, 256, 0, stream>>>(y, y, Wt + (size_t)(2 * i) * 65536, ST + (size_t)(2 * i) * 256);
    mfma_gemm<<<gblocks, 256, 0, stream>>>(y, x, Wt + (size_t)(2 * i + 1) * 65536, ST + (size_t)(2 * i + 1) * 256);
  }
  pool_kernel<<<dim3(N_GRAPHS, 8), 256, 0, stream>>>(x, pools + (size_t)NLAYERS * N_GRAPHS * HID, gstart);
  head_kernel<<<1, 1024, 0, stream>>>(pools, gstart, fcW, fcb, out);
}

// Round 4
// 645.854 us; speedup vs baseline: 3.8658x; 1.1150x over previous
//
#include <hip/hip_runtime.h>
#include <hip/hip_bf16.h>

#define N_NODES 50000
#define N_EDGES 400000
#define N_GRAPHS 64
#define HID 200
#define NUM_OUT 16
#define NLAYERS 5
#define CPAD 256            // padded channel count (K and N of GEMMs)
#define MPAD 50048          // padded row count (multiple of 128)
#define SCAN_B 196          // ceil(N_NODES/256)

typedef unsigned short ushort_t;
typedef short short8 __attribute__((ext_vector_type(8)));
typedef float f32x4 __attribute__((ext_vector_type(4)));

__device__ __forceinline__ float b2f(ushort_t u) {
  return __uint_as_float(((unsigned)u) << 16);
}
__device__ __forceinline__ ushort_t f2b(float f) {
  unsigned u = __float_as_uint(f);
  unsigned r = (u + 0x7FFFu + ((u >> 16) & 1u)) >> 16;
  return (ushort_t)r;
}

__device__ __forceinline__ void gload_lds16(const void* g, void* l) {
  __builtin_amdgcn_global_load_lds(
      (const __attribute__((address_space(1))) unsigned int*)g,
      (__attribute__((address_space(3))) unsigned int*)l, 16, 0, 0);
}

// ---------------------------------------------------------------------------
// node embedding -> bf16 padded [MPAD][256]; pad rows/channels = 0
__global__ void embed_kernel(const int* __restrict__ kind, const int* __restrict__ content,
                             const float* __restrict__ kind_emb, const float* __restrict__ inst2vec,
                             const float* __restrict__ type_emb, ushort_t* __restrict__ x) {
  long n = blockIdx.x; int ch = threadIdx.x;
  ushort_t v = 0;
  if (n < N_NODES && ch < HID) {
    int k = kind[n];
    float f = kind_emb[k * HID + ch];
    f += (k == 0) ? inst2vec[(size_t)content[n] * HID + ch] : type_emb[ch];
    v = f2b(f);
  }
  x[n * CPAD + ch] = v;
}

// edge-embedding table fp32 padded [60][256], pad = 0
__global__ void ecomb_kernel(const float* __restrict__ etype_emb, const float* __restrict__ epos_emb,
                             float* __restrict__ ecomb) {
  int code = blockIdx.x; int ch = threadIdx.x;
  float v = 0.f;
  if (ch < HID) v = etype_emb[(code / 20) * HID + ch] + epos_emb[(code % 20) * HID + ch];
  ecomb[code * CPAD + ch] = v;
}

// weights: bf16, transposed, padded.  Wt[g][n][k], g=2i -> W1[i], g=2i+1 -> W2[i]
__global__ void prep_w(const float* __restrict__ W1, const float* __restrict__ W2,
                       ushort_t* __restrict__ Wt) {
  int idx = blockIdx.x * 256 + threadIdx.x;   // 10*256*256 total
  int g = idx >> 16; int rem = idx & 65535; int n = rem >> 8; int k = rem & 255;
  float v = 0.f;
  if (n < HID && k < HID) {
    int i = g >> 1;
    v = (g & 1) ? W2[(size_t)i * HID * HID + (size_t)k * HID + n]
                : W1[(size_t)i * HID * HID + (size_t)k * HID + n];
  }
  Wt[idx] = f2b(v);
}

// epilogue tables: out = relu(acc*s + t); pad channels s=t=0 (keeps pads zero)
__global__ void prep_st(const float* __restrict__ b1, const float* __restrict__ bn_g,
                        const float* __restrict__ bn_b, const float* __restrict__ bn_m,
                        const float* __restrict__ bn_v, const float* __restrict__ b2,
                        float2* __restrict__ ST) {
  int idx = blockIdx.x * 256 + threadIdx.x;   // 10*256
  int g = idx >> 8, c = idx & 255;
  float s = 0.f, t = 0.f;
  if (c < HID) {
    int i = g >> 1;
    if (g & 1) { s = 1.f; t = b2[i * HID + c]; }
    else {
      float sc = bn_g[i * HID + c] * rsqrtf(bn_v[i * HID + c] + 1e-5f);
      s = sc; t = (b1[i * HID + c] - bn_m[i * HID + c]) * sc + bn_b[i * HID + c];
    }
  }
  ST[idx] = make_float2(s, t);
}

// CSR build
__global__ void hist_kernel(const int* __restrict__ dst, int* __restrict__ deg) {
  int e = blockIdx.x * 256 + threadIdx.x;
  if (e < N_EDGES) atomicAdd(&deg[dst[e]], 1);
}

// hierarchical scan
__global__ void scan1_kernel(const int* __restrict__ deg, int* __restrict__ bsum) {
  __shared__ int red[256];
  int b = blockIdx.x, t = threadIdx.x;
  int i = b * 256 + t;
  red[t] = (i < N_NODES) ? deg[i] : 0;
  __syncthreads();
  for (int off = 128; off > 0; off >>= 1) {
    if (t < off) red[t] += red[t + off];
    __syncthreads();
  }
  if (t == 0) bsum[b] = red[0];
}

__global__ void scan2_kernel(const int* __restrict__ bsum, int* __restrict__ bpre,
                             int* __restrict__ offs) {
  __shared__ int buf[256];
  int t = threadIdx.x;
  int v = (t < SCAN_B) ? bsum[t] : 0;
  buf[t] = v;
  __syncthreads();
  for (int off = 1; off < 256; off <<= 1) {
    int tv = (t >= off) ? buf[t - off] : 0;
    __syncthreads();
    buf[t] += tv;
    __syncthreads();
  }
  if (t < SCAN_B) bpre[t] = buf[t] - v;
  if (t == 255) offs[N_NODES] = buf[255];
}

__global__ void scan3_kernel(const int* __restrict__ deg, const int* __restrict__ bpre,
                             int* __restrict__ offs, int* __restrict__ cursor) {
  __shared__ int buf[256];
  int b = blockIdx.x, t = threadIdx.x;
  int i = b * 256 + t;
  int v = (i < N_NODES) ? deg[i] : 0;
  buf[t] = v;
  __syncthreads();
  for (int off = 1; off < 256; off <<= 1) {
    int tv = (t >= off) ? buf[t - off] : 0;
    __syncthreads();
    buf[t] += tv;
    __syncthreads();
  }
  if (i < N_NODES) {
    int e = bpre[b] + buf[t] - v;
    offs[i] = e; cursor[i] = e;
  }
}

__global__ void scatter_kernel(const int* __restrict__ src, const int* __restrict__ dst,
                               const int* __restrict__ etype, const int* __restrict__ epos,
                               int* __restrict__ cursor, int* __restrict__ e_src, int* __restrict__ e_code) {
  int e = blockIdx.x * 256 + threadIdx.x;
  if (e >= N_EDGES) return;
  int d = dst[e];
  int slot = atomicAdd(&cursor[d], 1);
  e_src[slot] = src[e];
  int p = epos[e]; if (p > 19) p = 19;
  e_code[slot] = etype[e] * 20 + p;
}

__global__ void gstart_kernel(const int* __restrict__ bv, int* __restrict__ gstart) {
  int g = threadIdx.x;
  if (g > N_GRAPHS) return;
  if (g == N_GRAPHS) { gstart[N_GRAPHS] = N_NODES; return; }
  int lo = 0, hi = N_NODES;
  while (lo < hi) { int mid = (lo + hi) >> 1; if (bv[mid] < g) lo = mid + 1; else hi = mid; }
  gstart[g] = lo;
}

// GINE aggregation in bf16: one wave per node; lane covers 4 channels
__global__ void agg_kernel(const ushort_t* __restrict__ x, ushort_t* __restrict__ y,
                           const int* __restrict__ offs, const int* __restrict__ e_src,
                           const int* __restrict__ e_code, const float* __restrict__ ecomb) {
  int w = threadIdx.x >> 6;
  int lane = threadIdx.x & 63;
  int n = blockIdx.x * 4 + w;
  if (n >= N_NODES) return;
  int s0 = offs[n], s1 = offs[n + 1];
  const ushort4* xv = (const ushort4*)x;
  float a0 = 0.f, a1 = 0.f, a2 = 0.f, a3 = 0.f;
  for (int j = s0; j < s1; ++j) {
    int s = e_src[j], code = e_code[j];
    ushort4 xs = xv[(size_t)s * 64 + lane];
    float4 ec = *(const float4*)(ecomb + (size_t)code * CPAD + lane * 4);
    a0 += fmaxf(b2f(xs.x) + ec.x, 0.f);
    a1 += fmaxf(b2f(xs.y) + ec.y, 0.f);
    a2 += fmaxf(b2f(xs.z) + ec.z, 0.f);
    a3 += fmaxf(b2f(xs.w) + ec.w, 0.f);
  }
  ushort4 xn = xv[(size_t)n * 64 + lane];
  ushort4 o;
  o.x = f2b(b2f(xn.x) + a0);
  o.y = f2b(b2f(xn.y) + a1);
  o.z = f2b(b2f(xn.z) + a2);
  o.w = f2b(b2f(xn.w) + a3);
  ((ushort4*)y)[(size_t)n * 64 + lane] = o;
}

// ---------------------------------------------------------------------------
// bf16 MFMA GEMM: BM=128, BN=256, BK=64; 4 waves, wave tile 64x128 (acc[4][8]).
__global__ __launch_bounds__(256, 2) void mfma_gemm(
    const ushort_t* __restrict__ A, ushort_t* __restrict__ C,
    const ushort_t* __restrict__ Wt, const float2* __restrict__ ST) {
  __shared__ char lds[48 * 1024];       // A: 0..16K (128 rows x 128B), B: 16K..48K
  char* A_l = lds;
  char* B_l = lds + 16384;
  const int tid = threadIdx.x;
  const int lane = tid & 63, wid = tid >> 6;
  const int wm = wid >> 1, wn = wid & 1;
  const size_t r0 = (size_t)blockIdx.x * 128;

  f32x4 acc[4][8];
  #pragma unroll
  for (int mi = 0; mi < 4; mi++)
    #pragma unroll
    for (int ni = 0; ni < 8; ni++) acc[mi][ni] = (f32x4){0.f, 0.f, 0.f, 0.f};

  const char* Ab = (const char*)A;
  const char* Wb = (const char*)Wt;

  for (int k0 = 0; k0 < CPAD; k0 += 64) {
    __syncthreads();   // protect previous iteration's LDS reads
    #pragma unroll
    for (int c = 0; c < 4; c++) {
      int d = tid * 16 + c * 4096;
      int rowd = d >> 7;
      int slot = (d >> 4) & 7;
      int lslot = slot ^ (rowd & 7);
      gload_lds16(Ab + (r0 + rowd) * 512 + k0 * 2 + lslot * 16, A_l + d);
    }
    #pragma unroll
    for (int c = 0; c < 8; c++) {
      int d = tid * 16 + c * 4096;
      int rowd = d >> 7;
      int slot = (d >> 4) & 7;
      int lslot = slot ^ (rowd & 7);
      gload_lds16(Wb + (size_t)rowd * 512 + k0 * 2 + lslot * 16, B_l + d);
    }
    __syncthreads();
    #pragma unroll
    for (int s = 0; s < 2; s++) {
      short8 bfr[8];
      #pragma unroll
      for (int ni = 0; ni < 8; ni++) {
        int brow = wn * 128 + ni * 16 + (lane & 15);
        int off = brow * 128 + (((s * 4 + (lane >> 4)) ^ (brow & 7)) << 4);
        bfr[ni] = *(const short8*)(B_l + off);
      }
      #pragma unroll
      for (int mi = 0; mi < 4; mi++) {
        int arow = wm * 64 + mi * 16 + (lane & 15);
        int off = arow * 128 + (((s * 4 + (lane >> 4)) ^ (arow & 7)) << 4);
        short8 af = *(const short8*)(A_l + off);
        #pragma unroll
        for (int ni = 0; ni < 8; ni++)
          acc[mi][ni] = __builtin_amdgcn_mfma_f32_16x16x32_bf16(af, bfr[ni], acc[mi][ni], 0, 0, 0);
      }
    }
  }

  #pragma unroll
  for (int ni = 0; ni < 8; ni++) {
    int col = wn * 128 + ni * 16 + (lane & 15);
    float2 st = ST[col];
    #pragma unroll
    for (int mi = 0; mi < 4; mi++) {
      int rbase = wm * 64 + mi * 16 + (lane >> 4) * 4;
      #pragma unroll
      for (int j = 0; j < 4; j++) {
        float v = fmaf(acc[mi][ni][j], st.x, st.y);
        v = fmaxf(v, 0.f);
        C[(r0 + rbase + j) * CPAD + col] = f2b(v);
      }
    }
  }
}

// per-graph partial sums: wave per row-stripe, ushort4/lane, register accum, 4 atomics/lane
__global__ void pool_kernel(const ushort_t* __restrict__ x, float* __restrict__ pool_sum,
                            const int* __restrict__ gstart) {
  int g = blockIdx.x, chunk = blockIdx.y;
  int w = threadIdx.x >> 6, lane = threadIdx.x & 63;
  int s = gstart[g], e = gstart[g + 1];
  int len = e - s;
  int per = (len + (int)gridDim.y - 1) / (int)gridDim.y;
  int cs = s + chunk * per; int ce = cs + per; if (ce > e) ce = e;
  if (cs >= ce) return;
  const ushort4* xv = (const ushort4*)x;
  float a0 = 0.f, a1 = 0.f, a2 = 0.f, a3 = 0.f;
  for (int n = cs + w; n < ce; n += 4) {
    ushort4 t = xv[(size_t)n * 64 + lane];
    a0 += b2f(t.x); a1 += b2f(t.y); a2 += b2f(t.z); a3 += b2f(t.w);
  }
  int c = lane * 4;
  if (c < HID) {
    atomicAdd(&pool_sum[g * HID + c + 0], a0);
    atomicAdd(&pool_sum[g * HID + c + 1], a1);
    atomicAdd(&pool_sum[g * HID + c + 2], a2);
    atomicAdd(&pool_sum[g * HID + c + 3], a3);
  }
}

// head stage 1: one block per (layer i, graph g); 256 threads as (cgroup 16, out 16).
// partial[i][g][o] = dot(pools[i,g,:], fcW[i,:,o]) * inv_cnt + fcb[i][o]
__global__ void head1_kernel(const float* __restrict__ pools, const int* __restrict__ gstart,
                             const float* __restrict__ fcW, const float* __restrict__ fcb,
                             float* __restrict__ partial) {
  __shared__ float red[256];
  int i = blockIdx.x, g = blockIdx.y;
  int t = threadIdx.x;
  int o = t & 15, cg = t >> 4;
  const float* ps = pools + (size_t)(i * N_GRAPHS + g) * HID;
  const float* w = fcW + (size_t)i * HID * NUM_OUT;
  float a = 0.f;
  for (int c = cg; c < HID; c += 16) a = fmaf(ps[c], w[c * NUM_OUT + o], a);
  red[t] = a;
  __syncthreads();
  #pragma unroll
  for (int off = 8; off > 0; off >>= 1) {
    if (cg < off) red[t] += red[t + off * 16];
    __syncthreads();
  }
  if (cg == 0) {
    int cnt = gstart[g + 1] - gstart[g];
    float inv = 1.f / (float)(cnt > 0 ? cnt : 1);
    partial[(i * N_GRAPHS + g) * NUM_OUT + o] = red[t] * inv + fcb[i * NUM_OUT + o];
  }
}

// head stage 2: sum the 6 layer partials
__global__ void head2_kernel(const float* __restrict__ partial, float* __restrict__ out) {
  int t = threadIdx.x;
  if (t >= N_GRAPHS * NUM_OUT) return;
  float acc = 0.f;
  #pragma unroll
  for (int i = 0; i < NLAYERS + 1; ++i) acc += partial[i * N_GRAPHS * NUM_OUT + t];
  out[t] = acc;
}

// ---------------------------------------------------------------------------
extern "C" void kernel_launch(void* const* d_in, const int* in_sizes, int n_in,
                              void* d_out, int out_size, void* d_ws, size_t ws_size,
                              hipStream_t stream) {
  const int*   node_kind    = (const int*)d_in[0];
  const int*   node_content = (const int*)d_in[1];
  const int*   edge_index   = (const int*)d_in[2];
  const int*   edge_type    = (const int*)d_in[3];
  const int*   edge_pos     = (const int*)d_in[4];
  const int*   batch_vec    = (const int*)d_in[5];
  const float* kind_emb     = (const float*)d_in[6];
  const float* inst2vec     = (const float*)d_in[7];
  const float* type_emb     = (const float*)d_in[8];
  const float* etype_emb    = (const float*)d_in[9];
  const float* epos_emb     = (const float*)d_in[10];
  const float* W1   = (const float*)d_in[11];
  const float* b1   = (const float*)d_in[12];
  const float* bn_g = (const float*)d_in[13];
  const float* bn_b = (const float*)d_in[14];
  const float* bn_m = (const float*)d_in[15];
  const float* bn_v = (const float*)d_in[16];
  const float* W2   = (const float*)d_in[17];
  const float* b2   = (const float*)d_in[18];
  const float* fcW  = (const float*)d_in[19];
  const float* fcb  = (const float*)d_in[20];
  float* out = (float*)d_out;

  char* ws = (char*)d_ws;
  ushort_t* x     = (ushort_t*)(ws + 0ull);           // MPAD*256*2 = 25,624,576
  ushort_t* y     = (ushort_t*)(ws + 25624576ull);    // 25,624,576
  ushort_t* Wt    = (ushort_t*)(ws + 51249152ull);    // 1,310,720
  float2*   ST    = (float2*)  (ws + 52559872ull);    // 20,480
  float*    ecomb = (float*)   (ws + 52580352ull);    // 61,440
  int*      deg   = (int*)     (ws + 52641792ull);    // 200,000
  int*      offs  = (int*)     (ws + 52841792ull);    // 200,016
  int*      cursor= (int*)     (ws + 53041824ull);    // 200,000
  int*      e_src = (int*)     (ws + 53241824ull);    // 1,600,000
  int*      e_code= (int*)     (ws + 54841824ull);    // 1,600,000
  int*      gstart= (int*)     (ws + 56441824ull);    // 260
  float*    pools = (float*)   (ws + 56442096ull);    // 307,200
  int*      bsum  = (int*)     (ws + 56749296ull);    // 784
  int*      bpre  = (int*)     (ws + 56750080ull);    // 784
  float*    partial=(float*)   (ws + 56750864ull);    // 6*64*16*4 = 24,576

  const int* srcp = edge_index;
  const int* dstp = edge_index + N_EDGES;

  hipMemsetAsync(deg, 0, N_NODES * sizeof(int), stream);
  hipMemsetAsync(pools, 0, (NLAYERS + 1) * N_GRAPHS * HID * sizeof(float), stream);
  hipMemsetAsync(y + (size_t)N_NODES * CPAD, 0, (size_t)(MPAD - N_NODES) * CPAD * 2, stream);

  prep_w<<<(10 * 256 * 256) / 256, 256, 0, stream>>>(W1, W2, Wt);
  prep_st<<<10, 256, 0, stream>>>(b1, bn_g, bn_b, bn_m, bn_v, b2, ST);
  ecomb_kernel<<<60, 256, 0, stream>>>(etype_emb, epos_emb, ecomb);
  embed_kernel<<<MPAD, 256, 0, stream>>>(node_kind, node_content, kind_emb, inst2vec, type_emb, x);
  hist_kernel<<<(N_EDGES + 255) / 256, 256, 0, stream>>>(dstp, deg);
  scan1_kernel<<<SCAN_B, 256, 0, stream>>>(deg, bsum);
  scan2_kernel<<<1, 256, 0, stream>>>(bsum, bpre, offs);
  scan3_kernel<<<SCAN_B, 256, 0, stream>>>(deg, bpre, offs, cursor);
  scatter_kernel<<<(N_EDGES + 255) / 256, 256, 0, stream>>>(srcp, dstp, edge_type, edge_pos,
                                                            cursor, e_src, e_code);
  gstart_kernel<<<1, 128, 0, stream>>>(batch_vec, gstart);

  const int gblocks = MPAD / 128;   // 391
  for (int i = 0; i < NLAYERS; ++i) {
    pool_kernel<<<dim3(N_GRAPHS, 8), 256, 0, stream>>>(x, pools + (size_t)i * N_GRAPHS * HID, gstart);
    agg_kernel<<<(N_NODES + 3) / 4, 256, 0, stream>>>(x, y, offs, e_src, e_code, ecomb);
    mfma_gemm<<<gblocks, 256, 0, stream>>>(y, y, Wt + (size_t)(2 * i) * 65536, ST + (size_t)(2 * i) * 256);
    mfma_gemm<<<gblocks, 256, 0, stream>>>(y, x, Wt + (size_t)(2 * i + 1) * 65536, ST + (size_t)(2 * i + 1) * 256);
  }
  pool_kernel<<<dim3(N_GRAPHS, 8), 256, 0, stream>>>(x, pools + (size_t)NLAYERS * N_GRAPHS * HID, gstart);
  head1_kernel<<<dim3(NLAYERS + 1, N_GRAPHS), 256, 0, stream>>>(pools, gstart, fcW, fcb, partial);
  head2_kernel<<<1, 1024, 0, stream>>>(partial, out);
}

// Round 5
// 565.747 us; speedup vs baseline: 4.4132x; 1.1416x over previous
//
#include <hip/hip_runtime.h>
#include <hip/hip_bf16.h>

#define N_NODES 50000
#define N_EDGES 400000
#define N_GRAPHS 64
#define HID 200
#define NUM_OUT 16
#define NLAYERS 5
#define CPAD 256            // padded channel count (K and N of GEMMs)
#define MPAD 50048          // padded row count (multiple of 64)
#define SCAN_B 196          // ceil(N_NODES/256)

typedef unsigned short ushort_t;
typedef short short8 __attribute__((ext_vector_type(8)));
typedef float f32x4 __attribute__((ext_vector_type(4)));

__device__ __forceinline__ float b2f(ushort_t u) {
  return __uint_as_float(((unsigned)u) << 16);
}
__device__ __forceinline__ ushort_t f2b(float f) {
  unsigned u = __float_as_uint(f);
  unsigned r = (u + 0x7FFFu + ((u >> 16) & 1u)) >> 16;
  return (ushort_t)r;
}

__device__ __forceinline__ void gload_lds16(const void* g, void* l) {
  __builtin_amdgcn_global_load_lds(
      (const __attribute__((address_space(1))) unsigned int*)g,
      (__attribute__((address_space(3))) unsigned int*)l, 16, 0, 0);
}

// ---------------------------------------------------------------------------
// node embedding -> bf16 padded [MPAD][256]; pad rows/channels = 0
__global__ void embed_kernel(const int* __restrict__ kind, const int* __restrict__ content,
                             const float* __restrict__ kind_emb, const float* __restrict__ inst2vec,
                             const float* __restrict__ type_emb, ushort_t* __restrict__ x) {
  long n = blockIdx.x; int ch = threadIdx.x;
  ushort_t v = 0;
  if (n < N_NODES && ch < HID) {
    int k = kind[n];
    float f = kind_emb[k * HID + ch];
    f += (k == 0) ? inst2vec[(size_t)content[n] * HID + ch] : type_emb[ch];
    v = f2b(f);
  }
  x[n * CPAD + ch] = v;
}

// edge-embedding table fp32 padded [60][256], pad = 0
__global__ void ecomb_kernel(const float* __restrict__ etype_emb, const float* __restrict__ epos_emb,
                             float* __restrict__ ecomb) {
  int code = blockIdx.x; int ch = threadIdx.x;
  float v = 0.f;
  if (ch < HID) v = etype_emb[(code / 20) * HID + ch] + epos_emb[(code % 20) * HID + ch];
  ecomb[code * CPAD + ch] = v;
}

// weights: bf16, transposed, padded.  Wt[g][n][k], g=2i -> W1[i], g=2i+1 -> W2[i]
__global__ void prep_w(const float* __restrict__ W1, const float* __restrict__ W2,
                       ushort_t* __restrict__ Wt) {
  int idx = blockIdx.x * 256 + threadIdx.x;   // 10*256*256 total
  int g = idx >> 16; int rem = idx & 65535; int n = rem >> 8; int k = rem & 255;
  float v = 0.f;
  if (n < HID && k < HID) {
    int i = g >> 1;
    v = (g & 1) ? W2[(size_t)i * HID * HID + (size_t)k * HID + n]
                : W1[(size_t)i * HID * HID + (size_t)k * HID + n];
  }
  Wt[idx] = f2b(v);
}

// epilogue tables: out = relu(acc*s + t); pad channels s=t=0 (keeps pads zero)
__global__ void prep_st(const float* __restrict__ b1, const float* __restrict__ bn_g,
                        const float* __restrict__ bn_b, const float* __restrict__ bn_m,
                        const float* __restrict__ bn_v, const float* __restrict__ b2,
                        float2* __restrict__ ST) {
  int idx = blockIdx.x * 256 + threadIdx.x;   // 10*256
  int g = idx >> 8, c = idx & 255;
  float s = 0.f, t = 0.f;
  if (c < HID) {
    int i = g >> 1;
    if (g & 1) { s = 1.f; t = b2[i * HID + c]; }
    else {
      float sc = bn_g[i * HID + c] * rsqrtf(bn_v[i * HID + c] + 1e-5f);
      s = sc; t = (b1[i * HID + c] - bn_m[i * HID + c]) * sc + bn_b[i * HID + c];
    }
  }
  ST[idx] = make_float2(s, t);
}

// CSR build
__global__ void hist_kernel(const int* __restrict__ dst, int* __restrict__ deg) {
  int e = blockIdx.x * 256 + threadIdx.x;
  if (e < N_EDGES) atomicAdd(&deg[dst[e]], 1);
}

// hierarchical scan
__global__ void scan1_kernel(const int* __restrict__ deg, int* __restrict__ bsum) {
  __shared__ int red[256];
  int b = blockIdx.x, t = threadIdx.x;
  int i = b * 256 + t;
  red[t] = (i < N_NODES) ? deg[i] : 0;
  __syncthreads();
  for (int off = 128; off > 0; off >>= 1) {
    if (t < off) red[t] += red[t + off];
    __syncthreads();
  }
  if (t == 0) bsum[b] = red[0];
}

__global__ void scan2_kernel(const int* __restrict__ bsum, int* __restrict__ bpre,
                             int* __restrict__ offs) {
  __shared__ int buf[256];
  int t = threadIdx.x;
  int v = (t < SCAN_B) ? bsum[t] : 0;
  buf[t] = v;
  __syncthreads();
  for (int off = 1; off < 256; off <<= 1) {
    int tv = (t >= off) ? buf[t - off] : 0;
    __syncthreads();
    buf[t] += tv;
    __syncthreads();
  }
  if (t < SCAN_B) bpre[t] = buf[t] - v;
  if (t == 255) offs[N_NODES] = buf[255];
}

__global__ void scan3_kernel(const int* __restrict__ deg, const int* __restrict__ bpre,
                             int* __restrict__ offs, int* __restrict__ cursor) {
  __shared__ int buf[256];
  int b = blockIdx.x, t = threadIdx.x;
  int i = b * 256 + t;
  int v = (i < N_NODES) ? deg[i] : 0;
  buf[t] = v;
  __syncthreads();
  for (int off = 1; off < 256; off <<= 1) {
    int tv = (t >= off) ? buf[t - off] : 0;
    __syncthreads();
    buf[t] += tv;
    __syncthreads();
  }
  if (i < N_NODES) {
    int e = bpre[b] + buf[t] - v;
    offs[i] = e; cursor[i] = e;
  }
}

// scatter edges: pack (src,code) into one int
__global__ void scatter_kernel(const int* __restrict__ src, const int* __restrict__ dst,
                               const int* __restrict__ etype, const int* __restrict__ epos,
                               int* __restrict__ cursor, int* __restrict__ e_pack) {
  int e = blockIdx.x * 256 + threadIdx.x;
  if (e >= N_EDGES) return;
  int d = dst[e];
  int slot = atomicAdd(&cursor[d], 1);
  int p = epos[e]; if (p > 19) p = 19;
  e_pack[slot] = (src[e] << 6) | (etype[e] * 20 + p);
}

__global__ void gstart_kernel(const int* __restrict__ bv, int* __restrict__ gstart) {
  int g = threadIdx.x;
  if (g > N_GRAPHS) return;
  if (g == N_GRAPHS) { gstart[N_GRAPHS] = N_NODES; return; }
  int lo = 0, hi = N_NODES;
  while (lo < hi) { int mid = (lo + hi) >> 1; if (bv[mid] < g) lo = mid + 1; else hi = mid; }
  gstart[g] = lo;
}

// GINE aggregation in bf16: one wave per node; lanes 0..49 cover the 200 live
// channels (ushort4 each); lanes 50..63 just keep the pad channels zeroed.
__global__ void agg_kernel(const ushort_t* __restrict__ x, ushort_t* __restrict__ y,
                           const int* __restrict__ offs, const int* __restrict__ e_pack,
                           const float* __restrict__ ecomb) {
  int w = threadIdx.x >> 6;
  int lane = threadIdx.x & 63;
  int n = blockIdx.x * 4 + w;
  if (n >= N_NODES) return;
  const ushort4* xv = (const ushort4*)x;
  const float4* ecv = (const float4*)ecomb;
  ushort4* yv = (ushort4*)y;
  if (lane >= 50) {
    yv[(size_t)n * 64 + lane] = make_ushort4(0, 0, 0, 0);
    return;
  }
  int s0 = offs[n], s1 = offs[n + 1];
  float a0 = 0.f, a1 = 0.f, a2 = 0.f, a3 = 0.f;
  #pragma unroll 2
  for (int j = s0; j < s1; ++j) {
    int pk = e_pack[j];
    int s = pk >> 6, code = pk & 63;
    ushort4 xs = xv[(size_t)s * 64 + lane];
    float4 ec = ecv[(size_t)code * 64 + lane];
    a0 += fmaxf(b2f(xs.x) + ec.x, 0.f);
    a1 += fmaxf(b2f(xs.y) + ec.y, 0.f);
    a2 += fmaxf(b2f(xs.z) + ec.z, 0.f);
    a3 += fmaxf(b2f(xs.w) + ec.w, 0.f);
  }
  ushort4 xn = xv[(size_t)n * 64 + lane];
  ushort4 o;
  o.x = f2b(b2f(xn.x) + a0);
  o.y = f2b(b2f(xn.y) + a1);
  o.z = f2b(b2f(xn.z) + a2);
  o.w = f2b(b2f(xn.w) + a3);
  yv[(size_t)n * 64 + lane] = o;
}

// ---------------------------------------------------------------------------
// Fused layer: X = relu(relu(BN(Y@W1)) @ W2 + b2), all in one kernel.
// BM=64, 4 waves; wave tile 64x64 (wn = wave id over N).  Phase A writes the
// 64x256 bf16 intermediate T into LDS (swizzled), phase B consumes it as the
// MFMA A-operand.  Saves the 51.2 MB/layer HBM round-trip of the intermediate.
__global__ __launch_bounds__(256, 2) void fused_layer(
    const ushort_t* __restrict__ Y, ushort_t* __restrict__ X,
    const ushort_t* __restrict__ W1t, const ushort_t* __restrict__ W2t,
    const float2* __restrict__ ST1, const float2* __restrict__ ST2) {
  __shared__ char lds[72 * 1024];
  char* A_l = lds;              //  8KB: 64 rows x 128B (A k-tile)
  char* W_l = lds + 8192;       // 32KB: 256 rows x 128B (W1/W2 k-tile)
  char* T_l = lds + 40960;      // 32KB: 64 rows x 512B (intermediate, swizzled)
  const int tid = threadIdx.x;
  const int lane = tid & 63, wn = tid >> 6;
  const size_t r0 = (size_t)blockIdx.x * 64;
  const char* Ab = (const char*)Y;

  f32x4 acc[4][4];
  #pragma unroll
  for (int mi = 0; mi < 4; mi++)
    #pragma unroll
    for (int ni = 0; ni < 4; ni++) acc[mi][ni] = (f32x4){0.f, 0.f, 0.f, 0.f};

  // ---- phase A: acc = Y_tile @ W1 ----
  for (int k0 = 0; k0 < CPAD; k0 += 64) {
    __syncthreads();
    #pragma unroll
    for (int c = 0; c < 2; c++) {
      int d = tid * 16 + c * 4096;
      int rowd = d >> 7, slot = (d >> 4) & 7, lslot = slot ^ (rowd & 7);
      gload_lds16(Ab + (r0 + rowd) * 512 + k0 * 2 + lslot * 16, A_l + d);
    }
    #pragma unroll
    for (int c = 0; c < 8; c++) {
      int d = tid * 16 + c * 4096;
      int rowd = d >> 7, slot = (d >> 4) & 7, lslot = slot ^ (rowd & 7);
      gload_lds16((const char*)W1t + (size_t)rowd * 512 + k0 * 2 + lslot * 16, W_l + d);
    }
    __syncthreads();
    #pragma unroll
    for (int s = 0; s < 2; s++) {
      short8 bfr[4];
      #pragma unroll
      for (int ni = 0; ni < 4; ni++) {
        int brow = wn * 64 + ni * 16 + (lane & 15);
        int off = brow * 128 + (((s * 4 + (lane >> 4)) ^ (brow & 7)) << 4);
        bfr[ni] = *(const short8*)(W_l + off);
      }
      #pragma unroll
      for (int mi = 0; mi < 4; mi++) {
        int arow = mi * 16 + (lane & 15);
        int off = arow * 128 + (((s * 4 + (lane >> 4)) ^ (arow & 7)) << 4);
        short8 af = *(const short8*)(A_l + off);
        #pragma unroll
        for (int ni = 0; ni < 4; ni++)
          acc[mi][ni] = __builtin_amdgcn_mfma_f32_16x16x32_bf16(af, bfr[ni], acc[mi][ni], 0, 0, 0);
      }
    }
  }

  // ---- T = relu(BN(acc)) -> LDS (bf16, swizzled rows of 512B) ----
  #pragma unroll
  for (int ni = 0; ni < 4; ni++) {
    int col = wn * 64 + ni * 16 + (lane & 15);
    float2 st = ST1[col];
    #pragma unroll
    for (int mi = 0; mi < 4; mi++) {
      int rbase = mi * 16 + (lane >> 4) * 4;
      #pragma unroll
      for (int j = 0; j < 4; j++) {
        int row = rbase + j;
        float v = fmaxf(fmaf(acc[mi][ni][j], st.x, st.y), 0.f);
        int boff = row * 512 + ((((col >> 3) ^ (row & 7)) << 4) | ((col & 7) * 2));
        *(ushort_t*)(T_l + boff) = f2b(v);
      }
    }
  }
  #pragma unroll
  for (int mi = 0; mi < 4; mi++)
    #pragma unroll
    for (int ni = 0; ni < 4; ni++) acc[mi][ni] = (f32x4){0.f, 0.f, 0.f, 0.f};

  // ---- phase B: acc = T @ W2 ----
  for (int k0 = 0; k0 < CPAD; k0 += 64) {
    __syncthreads();   // waves done reading W_l (prev iter) / T written (first iter)
    #pragma unroll
    for (int c = 0; c < 8; c++) {
      int d = tid * 16 + c * 4096;
      int rowd = d >> 7, slot = (d >> 4) & 7, lslot = slot ^ (rowd & 7);
      gload_lds16((const char*)W2t + (size_t)rowd * 512 + k0 * 2 + lslot * 16, W_l + d);
    }
    __syncthreads();
    #pragma unroll
    for (int s = 0; s < 2; s++) {
      short8 bfr[4];
      #pragma unroll
      for (int ni = 0; ni < 4; ni++) {
        int brow = wn * 64 + ni * 16 + (lane & 15);
        int off = brow * 128 + (((s * 4 + (lane >> 4)) ^ (brow & 7)) << 4);
        bfr[ni] = *(const short8*)(W_l + off);
      }
      #pragma unroll
      for (int mi = 0; mi < 4; mi++) {
        int arow = mi * 16 + (lane & 15);
        int off = arow * 512 + k0 * 2 + (((s * 4 + (lane >> 4)) ^ (arow & 7)) << 4);
        short8 af = *(const short8*)(T_l + off);
        #pragma unroll
        for (int ni = 0; ni < 4; ni++)
          acc[mi][ni] = __builtin_amdgcn_mfma_f32_16x16x32_bf16(af, bfr[ni], acc[mi][ni], 0, 0, 0);
      }
    }
  }

  // ---- epilogue: X = relu(acc + b2) ----
  #pragma unroll
  for (int ni = 0; ni < 4; ni++) {
    int col = wn * 64 + ni * 16 + (lane & 15);
    float2 st = ST2[col];
    #pragma unroll
    for (int mi = 0; mi < 4; mi++) {
      int rbase = mi * 16 + (lane >> 4) * 4;
      #pragma unroll
      for (int j = 0; j < 4; j++) {
        float v = fmaxf(fmaf(acc[mi][ni][j], st.x, st.y), 0.f);
        X[(r0 + rbase + j) * CPAD + col] = f2b(v);
      }
    }
  }
}

// per-graph partial sums: wave per row-stripe, lanes 0..49, register accum
__global__ void pool_kernel(const ushort_t* __restrict__ x, float* __restrict__ pool_sum,
                            const int* __restrict__ gstart) {
  int g = blockIdx.x, chunk = blockIdx.y;
  int w = threadIdx.x >> 6, lane = threadIdx.x & 63;
  if (lane >= 50) return;
  int s = gstart[g], e = gstart[g + 1];
  int len = e - s;
  int per = (len + (int)gridDim.y - 1) / (int)gridDim.y;
  int cs = s + chunk * per; int ce = cs + per; if (ce > e) ce = e;
  if (cs >= ce) return;
  const ushort4* xv = (const ushort4*)x;
  float a0 = 0.f, a1 = 0.f, a2 = 0.f, a3 = 0.f;
  for (int n = cs + w; n < ce; n += 4) {
    ushort4 t = xv[(size_t)n * 64 + lane];
    a0 += b2f(t.x); a1 += b2f(t.y); a2 += b2f(t.z); a3 += b2f(t.w);
  }
  int c = lane * 4;
  atomicAdd(&pool_sum[g * HID + c + 0], a0);
  atomicAdd(&pool_sum[g * HID + c + 1], a1);
  atomicAdd(&pool_sum[g * HID + c + 2], a2);
  atomicAdd(&pool_sum[g * HID + c + 3], a3);
}

// head stage 1: one block per (layer i, graph g)
__global__ void head1_kernel(const float* __restrict__ pools, const int* __restrict__ gstart,
                             const float* __restrict__ fcW, const float* __restrict__ fcb,
                             float* __restrict__ partial) {
  __shared__ float red[256];
  int i = blockIdx.x, g = blockIdx.y;
  int t = threadIdx.x;
  int o = t & 15, cg = t >> 4;
  const float* ps = pools + (size_t)(i * N_GRAPHS + g) * HID;
  const float* w = fcW + (size_t)i * HID * NUM_OUT;
  float a = 0.f;
  for (int c = cg; c < HID; c += 16) a = fmaf(ps[c], w[c * NUM_OUT + o], a);
  red[t] = a;
  __syncthreads();
  #pragma unroll
  for (int off = 8; off > 0; off >>= 1) {
    if (cg < off) red[t] += red[t + off * 16];
    __syncthreads();
  }
  if (cg == 0) {
    int cnt = gstart[g + 1] - gstart[g];
    float inv = 1.f / (float)(cnt > 0 ? cnt : 1);
    partial[(i * N_GRAPHS + g) * NUM_OUT + o] = red[t] * inv + fcb[i * NUM_OUT + o];
  }
}

// head stage 2: sum the 6 layer partials
__global__ void head2_kernel(const float* __restrict__ partial, float* __restrict__ out) {
  int t = threadIdx.x;
  if (t >= N_GRAPHS * NUM_OUT) return;
  float acc = 0.f;
  #pragma unroll
  for (int i = 0; i < NLAYERS + 1; ++i) acc += partial[i * N_GRAPHS * NUM_OUT + t];
  out[t] = acc;
}

// ---------------------------------------------------------------------------
extern "C" void kernel_launch(void* const* d_in, const int* in_sizes, int n_in,
                              void* d_out, int out_size, void* d_ws, size_t ws_size,
                              hipStream_t stream) {
  const int*   node_kind    = (const int*)d_in[0];
  const int*   node_content = (const int*)d_in[1];
  const int*   edge_index   = (const int*)d_in[2];
  const int*   edge_type    = (const int*)d_in[3];
  const int*   edge_pos     = (const int*)d_in[4];
  const int*   batch_vec    = (const int*)d_in[5];
  const float* kind_emb     = (const float*)d_in[6];
  const float* inst2vec     = (const float*)d_in[7];
  const float* type_emb     = (const float*)d_in[8];
  const float* etype_emb    = (const float*)d_in[9];
  const float* epos_emb     = (const float*)d_in[10];
  const float* W1   = (const float*)d_in[11];
  const float* b1   = (const float*)d_in[12];
  const float* bn_g = (const float*)d_in[13];
  const float* bn_b = (const float*)d_in[14];
  const float* bn_m = (const float*)d_in[15];
  const float* bn_v = (const float*)d_in[16];
  const float* W2   = (const float*)d_in[17];
  const float* b2   = (const float*)d_in[18];
  const float* fcW  = (const float*)d_in[19];
  const float* fcb  = (const float*)d_in[20];
  float* out = (float*)d_out;

  char* ws = (char*)d_ws;
  ushort_t* x     = (ushort_t*)(ws + 0ull);           // MPAD*256*2 = 25,624,576
  ushort_t* y     = (ushort_t*)(ws + 25624576ull);    // 25,624,576
  ushort_t* Wt    = (ushort_t*)(ws + 51249152ull);    // 1,310,720
  float2*   ST    = (float2*)  (ws + 52559872ull);    // 20,480
  float*    ecomb = (float*)   (ws + 52580352ull);    // 61,440
  int*      deg   = (int*)     (ws + 52641792ull);    // 200,000
  int*      offs  = (int*)     (ws + 52841792ull);    // 200,016
  int*      cursor= (int*)     (ws + 53041824ull);    // 200,000
  int*      e_pack= (int*)     (ws + 53241824ull);    // 1,600,000
  int*      gstart= (int*)     (ws + 54841824ull);    // 260
  float*    pools = (float*)   (ws + 54842096ull);    // 307,200
  int*      bsum  = (int*)     (ws + 55149296ull);    // 784
  int*      bpre  = (int*)     (ws + 55150080ull);    // 784
  float*    partial=(float*)   (ws + 55150864ull);    // 24,576

  const int* srcp = edge_index;
  const int* dstp = edge_index + N_EDGES;

  hipMemsetAsync(deg, 0, N_NODES * sizeof(int), stream);
  hipMemsetAsync(pools, 0, (NLAYERS + 1) * N_GRAPHS * HID * sizeof(float), stream);
  // zero pad rows of y once per launch (agg does not write them)
  hipMemsetAsync(y + (size_t)N_NODES * CPAD, 0, (size_t)(MPAD - N_NODES) * CPAD * 2, stream);

  prep_w<<<(10 * 256 * 256) / 256, 256, 0, stream>>>(W1, W2, Wt);
  prep_st<<<10, 256, 0, stream>>>(b1, bn_g, bn_b, bn_m, bn_v, b2, ST);
  ecomb_kernel<<<60, 256, 0, stream>>>(etype_emb, epos_emb, ecomb);
  embed_kernel<<<MPAD, 256, 0, stream>>>(node_kind, node_content, kind_emb, inst2vec, type_emb, x);
  hist_kernel<<<(N_EDGES + 255) / 256, 256, 0, stream>>>(dstp, deg);
  scan1_kernel<<<SCAN_B, 256, 0, stream>>>(deg, bsum);
  scan2_kernel<<<1, 256, 0, stream>>>(bsum, bpre, offs);
  scan3_kernel<<<SCAN_B, 256, 0, stream>>>(deg, bpre, offs, cursor);
  scatter_kernel<<<(N_EDGES + 255) / 256, 256, 0, stream>>>(srcp, dstp, edge_type, edge_pos,
                                                            cursor, e_pack);
  gstart_kernel<<<1, 128, 0, stream>>>(batch_vec, gstart);

  const int fblocks = MPAD / 64;   // 782
  for (int i = 0; i < NLAYERS; ++i) {
    pool_kernel<<<dim3(N_GRAPHS, 8), 256, 0, stream>>>(x, pools + (size_t)i * N_GRAPHS * HID, gstart);
    agg_kernel<<<(N_NODES + 3) / 4, 256, 0, stream>>>(x, y, offs, e_pack, ecomb);
    fused_layer<<<fblocks, 256, 0, stream>>>(y, x,
        Wt + (size_t)(2 * i) * 65536, Wt + (size_t)(2 * i + 1) * 65536,
        ST + (size_t)(2 * i) * 256, ST + (size_t)(2 * i + 1) * 256);
  }
  pool_kernel<<<dim3(N_GRAPHS, 8), 256, 0, stream>>>(x, pools + (size_t)NLAYERS * N_GRAPHS * HID, gstart);
  head1_kernel<<<dim3(NLAYERS + 1, N_GRAPHS), 256, 0, stream>>>(pools, gstart, fcW, fcb, partial);
  head2_kernel<<<1, 1024, 0, stream>>>(partial, out);
}

// Round 6
// 452.266 us; speedup vs baseline: 5.5205x; 1.2509x over previous
//
#include <hip/hip_runtime.h>
#include <hip/hip_bf16.h>

#define N_NODES 50000
#define N_EDGES 400000
#define N_GRAPHS 64
#define HID 200
#define NUM_OUT 16
#define NLAYERS 5
#define CPAD 256            // padded channel count (K and N of GEMMs)
#define MPAD 50048          // padded row count (multiple of 64)
#define SCAN_B 196          // ceil(N_NODES/256)
#define EROWS 32            // rows per embed block (MPAD % 32 == 0)

typedef unsigned short ushort_t;
typedef short short8 __attribute__((ext_vector_type(8)));
typedef float f32x4 __attribute__((ext_vector_type(4)));

__device__ __forceinline__ float b2f(ushort_t u) {
  return __uint_as_float(((unsigned)u) << 16);
}
__device__ __forceinline__ ushort_t f2b(float f) {
  unsigned u = __float_as_uint(f);
  unsigned r = (u + 0x7FFFu + ((u >> 16) & 1u)) >> 16;
  return (ushort_t)r;
}

__device__ __forceinline__ void gload_lds16(const void* g, void* l) {
  __builtin_amdgcn_global_load_lds(
      (const __attribute__((address_space(1))) unsigned int*)g,
      (__attribute__((address_space(3))) unsigned int*)l, 16, 0, 0);
}

// ---------------------------------------------------------------------------
// embed + pool0 fused: 32 rows per block, thread = column.  Indices staged in
// LDS; per-graph register accumulation of the fp32 embedding, flushed on graph
// change (batch_vec is sorted).
__global__ __launch_bounds__(256) void embed_pool(
    const int* __restrict__ kind, const int* __restrict__ content,
    const float* __restrict__ kind_emb, const float* __restrict__ inst2vec,
    const float* __restrict__ type_emb, const int* __restrict__ bv,
    ushort_t* __restrict__ x, float* __restrict__ pool0) {
  __shared__ int k_s[EROWS], c_s[EROWS], g_s[EROWS];
  int t = threadIdx.x;
  size_t r0 = (size_t)blockIdx.x * EROWS;
  if (t < EROWS) {
    size_t r = r0 + t;
    int k = 0, cn = 0, g = -1;
    if (r < N_NODES) { k = kind[r]; cn = content[r]; g = bv[r]; }
    k_s[t] = k; c_s[t] = cn; g_s[t] = g;
  }
  __syncthreads();
  int c = t;
  float pacc = 0.f; int gcur = -1;
  #pragma unroll 2
  for (int rr = 0; rr < EROWS; ++rr) {
    size_t r = r0 + rr;
    if (r < N_NODES) {
      float f = 0.f;
      if (c < HID) {
        int k = k_s[rr];
        f = kind_emb[k * HID + c] +
            ((k == 0) ? inst2vec[(size_t)c_s[rr] * HID + c] : type_emb[c]);
      }
      x[r * CPAD + c] = f2b(f);
      int g = g_s[rr];
      if (g != gcur) {
        if (gcur >= 0 && c < HID) atomicAdd(&pool0[gcur * HID + c], pacc);
        pacc = 0.f; gcur = g;
      }
      pacc += f;
    } else {
      x[r * CPAD + c] = 0;
    }
  }
  if (gcur >= 0 && c < HID) atomicAdd(&pool0[gcur * HID + c], pacc);
}

// edge-embedding table fp32 padded [61][256]; row 60 = -1e9 (dummy edges)
__global__ void ecomb_kernel(const float* __restrict__ etype_emb, const float* __restrict__ epos_emb,
                             float* __restrict__ ecomb) {
  int code = blockIdx.x; int ch = threadIdx.x;
  float v;
  if (code == 60) v = -1e9f;
  else if (ch < HID) v = etype_emb[(code / 20) * HID + ch] + epos_emb[(code % 20) * HID + ch];
  else v = 0.f;
  ecomb[code * CPAD + ch] = v;
}

// weights: bf16, transposed, padded.  Wt[g][n][k], g=2i -> W1[i], g=2i+1 -> W2[i]
__global__ void prep_w(const float* __restrict__ W1, const float* __restrict__ W2,
                       ushort_t* __restrict__ Wt) {
  int idx = blockIdx.x * 256 + threadIdx.x;   // 10*256*256 total
  int g = idx >> 16; int rem = idx & 65535; int n = rem >> 8; int k = rem & 255;
  float v = 0.f;
  if (n < HID && k < HID) {
    int i = g >> 1;
    v = (g & 1) ? W2[(size_t)i * HID * HID + (size_t)k * HID + n]
                : W1[(size_t)i * HID * HID + (size_t)k * HID + n];
  }
  Wt[idx] = f2b(v);
}

// epilogue tables: out = relu(acc*s + t); pad channels s=t=0 (keeps pads zero)
__global__ void prep_st(const float* __restrict__ b1, const float* __restrict__ bn_g,
                        const float* __restrict__ bn_b, const float* __restrict__ bn_m,
                        const float* __restrict__ bn_v, const float* __restrict__ b2,
                        float2* __restrict__ ST) {
  int idx = blockIdx.x * 256 + threadIdx.x;   // 10*256
  int g = idx >> 8, c = idx & 255;
  float s = 0.f, t = 0.f;
  if (c < HID) {
    int i = g >> 1;
    if (g & 1) { s = 1.f; t = b2[i * HID + c]; }
    else {
      float sc = bn_g[i * HID + c] * rsqrtf(bn_v[i * HID + c] + 1e-5f);
      s = sc; t = (b1[i * HID + c] - bn_m[i * HID + c]) * sc + bn_b[i * HID + c];
    }
  }
  ST[idx] = make_float2(s, t);
}

// CSR build (padded degrees: multiple of 4)
__global__ void hist_kernel(const int* __restrict__ dst, int* __restrict__ deg) {
  int e = blockIdx.x * 256 + threadIdx.x;
  if (e < N_EDGES) atomicAdd(&deg[dst[e]], 1);
}

__global__ void scan1_kernel(const int* __restrict__ deg, int* __restrict__ bsum) {
  __shared__ int red[256];
  int b = blockIdx.x, t = threadIdx.x;
  int i = b * 256 + t;
  red[t] = (i < N_NODES) ? ((deg[i] + 3) & ~3) : 0;
  __syncthreads();
  for (int off = 128; off > 0; off >>= 1) {
    if (t < off) red[t] += red[t + off];
    __syncthreads();
  }
  if (t == 0) bsum[b] = red[0];
}

// scan2 + gstart (merged): block-sum scan; threads 0..64 also binary-search
// graph boundaries in sorted batch_vec.
__global__ void scan2_kernel(const int* __restrict__ bsum, int* __restrict__ bpre,
                             int* __restrict__ offs, const int* __restrict__ bv,
                             int* __restrict__ gstart) {
  __shared__ int buf[256];
  int t = threadIdx.x;
  if (t <= N_GRAPHS) {
    if (t == N_GRAPHS) gstart[N_GRAPHS] = N_NODES;
    else {
      int lo = 0, hi = N_NODES;
      while (lo < hi) { int mid = (lo + hi) >> 1; if (bv[mid] < t) lo = mid + 1; else hi = mid; }
      gstart[t] = lo;
    }
  }
  int v = (t < SCAN_B) ? bsum[t] : 0;
  buf[t] = v;
  __syncthreads();
  for (int off = 1; off < 256; off <<= 1) {
    int tv = (t >= off) ? buf[t - off] : 0;
    __syncthreads();
    buf[t] += tv;
    __syncthreads();
  }
  if (t < SCAN_B) bpre[t] = buf[t] - v;
  if (t == 255) offs[N_NODES] = buf[255];
}

__global__ void scan3_kernel(const int* __restrict__ deg, const int* __restrict__ bpre,
                             int* __restrict__ offs, int* __restrict__ cursor) {
  __shared__ int buf[256];
  int b = blockIdx.x, t = threadIdx.x;
  int i = b * 256 + t;
  int v = (i < N_NODES) ? ((deg[i] + 3) & ~3) : 0;
  buf[t] = v;
  __syncthreads();
  for (int off = 1; off < 256; off <<= 1) {
    int tv = (t >= off) ? buf[t - off] : 0;
    __syncthreads();
    buf[t] += tv;
    __syncthreads();
  }
  if (i < N_NODES) {
    int e = bpre[b] + buf[t] - v;
    offs[i] = e; cursor[i] = e;
  }
}

// scatter real edges: pack (src,code) into one int
__global__ void scatter_kernel(const int* __restrict__ src, const int* __restrict__ dst,
                               const int* __restrict__ etype, const int* __restrict__ epos,
                               int* __restrict__ cursor, int* __restrict__ e_pack) {
  int e = blockIdx.x * 256 + threadIdx.x;
  if (e >= N_EDGES) return;
  int d = dst[e];
  int slot = atomicAdd(&cursor[d], 1);
  int p = epos[e]; if (p > 19) p = 19;
  e_pack[slot] = (src[e] << 6) | (etype[e] * 20 + p);
}

// fill padding slots with dummy edges: self-src + ecomb code 60 (-1e9 -> relu 0)
__global__ void fill_kernel(const int* __restrict__ cursor, const int* __restrict__ offs,
                            int* __restrict__ e_pack) {
  int n = blockIdx.x * 256 + threadIdx.x;
  if (n >= N_NODES) return;
  int d = (n << 6) | 60;
  int e = offs[n + 1];
  for (int j = cursor[n]; j < e; ++j) e_pack[j] = d;
}

// GINE aggregation: one wave per node, lanes 0..49 cover the 200 live channels.
// Padded degree (multiple of 4) -> guard-free 4-wide unrolled gather pipeline.
__global__ void agg_kernel(const ushort_t* __restrict__ x, ushort_t* __restrict__ y,
                           const int* __restrict__ offs, const int* __restrict__ e_pack,
                           const float* __restrict__ ecomb) {
  int w = threadIdx.x >> 6;
  int lane = threadIdx.x & 63;
  int n = blockIdx.x * 4 + w;
  if (n >= N_NODES) return;
  const ushort4* xv = (const ushort4*)x;
  const float4* ecv = (const float4*)ecomb;
  ushort4* yv = (ushort4*)y;
  if (lane >= 50) {
    yv[(size_t)n * 64 + lane] = make_ushort4(0, 0, 0, 0);
    return;
  }
  int s0 = offs[n], s1 = offs[n + 1];
  float a0 = 0.f, a1 = 0.f, a2 = 0.f, a3 = 0.f;
  for (int j = s0; j < s1; j += 4) {
    int pk0 = e_pack[j + 0], pk1 = e_pack[j + 1];
    int pk2 = e_pack[j + 2], pk3 = e_pack[j + 3];
    ushort4 x0 = xv[(size_t)(pk0 >> 6) * 64 + lane];
    ushort4 x1 = xv[(size_t)(pk1 >> 6) * 64 + lane];
    ushort4 x2 = xv[(size_t)(pk2 >> 6) * 64 + lane];
    ushort4 x3 = xv[(size_t)(pk3 >> 6) * 64 + lane];
    float4 e0 = ecv[(size_t)(pk0 & 63) * 64 + lane];
    float4 e1 = ecv[(size_t)(pk1 & 63) * 64 + lane];
    float4 e2 = ecv[(size_t)(pk2 & 63) * 64 + lane];
    float4 e3 = ecv[(size_t)(pk3 & 63) * 64 + lane];
    a0 += fmaxf(b2f(x0.x) + e0.x, 0.f) + fmaxf(b2f(x1.x) + e1.x, 0.f)
        + fmaxf(b2f(x2.x) + e2.x, 0.f) + fmaxf(b2f(x3.x) + e3.x, 0.f);
    a1 += fmaxf(b2f(x0.y) + e0.y, 0.f) + fmaxf(b2f(x1.y) + e1.y, 0.f)
        + fmaxf(b2f(x2.y) + e2.y, 0.f) + fmaxf(b2f(x3.y) + e3.y, 0.f);
    a2 += fmaxf(b2f(x0.z) + e0.z, 0.f) + fmaxf(b2f(x1.z) + e1.z, 0.f)
        + fmaxf(b2f(x2.z) + e2.z, 0.f) + fmaxf(b2f(x3.z) + e3.z, 0.f);
    a3 += fmaxf(b2f(x0.w) + e0.w, 0.f) + fmaxf(b2f(x1.w) + e1.w, 0.f)
        + fmaxf(b2f(x2.w) + e2.w, 0.f) + fmaxf(b2f(x3.w) + e3.w, 0.f);
  }
  ushort4 xn = xv[(size_t)n * 64 + lane];
  ushort4 o;
  o.x = f2b(b2f(xn.x) + a0);
  o.y = f2b(b2f(xn.y) + a1);
  o.z = f2b(b2f(xn.z) + a2);
  o.w = f2b(b2f(xn.w) + a3);
  yv[(size_t)n * 64 + lane] = o;
}

// ---------------------------------------------------------------------------
// Fused layer: X = relu(relu(BN(Y@W1)) @ W2 + b2) + per-graph pooling of X
// into pools_out (the next layer's jumping-knowledge pool), all in one kernel.
__global__ __launch_bounds__(256, 2) void fused_layer(
    const ushort_t* __restrict__ Y, ushort_t* __restrict__ X,
    const ushort_t* __restrict__ W1t, const ushort_t* __restrict__ W2t,
    const float2* __restrict__ ST1, const float2* __restrict__ ST2,
    const int* __restrict__ bv, const int* __restrict__ gstart,
    float* __restrict__ pools_out) {
  __shared__ char lds[72 * 1024];
  char* A_l = lds;              //  8KB: 64 rows x 128B (A k-tile)
  char* W_l = lds + 8192;       // 32KB: 256 rows x 128B (W1/W2 k-tile)
  char* T_l = lds + 40960;      // 32KB: 64 rows x 512B (intermediate, swizzled)
  const int tid = threadIdx.x;
  const int lane = tid & 63, wn = tid >> 6;
  const size_t r0 = (size_t)blockIdx.x * 64;
  const char* Ab = (const char*)Y;

  f32x4 acc[4][4];
  #pragma unroll
  for (int mi = 0; mi < 4; mi++)
    #pragma unroll
    for (int ni = 0; ni < 4; ni++) acc[mi][ni] = (f32x4){0.f, 0.f, 0.f, 0.f};

  // ---- phase A: acc = Y_tile @ W1 ----
  for (int k0 = 0; k0 < CPAD; k0 += 64) {
    __syncthreads();
    #pragma unroll
    for (int c = 0; c < 2; c++) {
      int d = tid * 16 + c * 4096;
      int rowd = d >> 7, slot = (d >> 4) & 7, lslot = slot ^ (rowd & 7);
      gload_lds16(Ab + (r0 + rowd) * 512 + k0 * 2 + lslot * 16, A_l + d);
    }
    #pragma unroll
    for (int c = 0; c < 8; c++) {
      int d = tid * 16 + c * 4096;
      int rowd = d >> 7, slot = (d >> 4) & 7, lslot = slot ^ (rowd & 7);
      gload_lds16((const char*)W1t + (size_t)rowd * 512 + k0 * 2 + lslot * 16, W_l + d);
    }
    __syncthreads();
    #pragma unroll
    for (int s = 0; s < 2; s++) {
      short8 bfr[4];
      #pragma unroll
      for (int ni = 0; ni < 4; ni++) {
        int brow = wn * 64 + ni * 16 + (lane & 15);
        int off = brow * 128 + (((s * 4 + (lane >> 4)) ^ (brow & 7)) << 4);
        bfr[ni] = *(const short8*)(W_l + off);
      }
      #pragma unroll
      for (int mi = 0; mi < 4; mi++) {
        int arow = mi * 16 + (lane & 15);
        int off = arow * 128 + (((s * 4 + (lane >> 4)) ^ (arow & 7)) << 4);
        short8 af = *(const short8*)(A_l + off);
        #pragma unroll
        for (int ni = 0; ni < 4; ni++)
          acc[mi][ni] = __builtin_amdgcn_mfma_f32_16x16x32_bf16(af, bfr[ni], acc[mi][ni], 0, 0, 0);
      }
    }
  }

  // ---- T = relu(BN(acc)) -> LDS (bf16, swizzled rows of 512B) ----
  #pragma unroll
  for (int ni = 0; ni < 4; ni++) {
    int col = wn * 64 + ni * 16 + (lane & 15);
    float2 st = ST1[col];
    #pragma unroll
    for (int mi = 0; mi < 4; mi++) {
      int rbase = mi * 16 + (lane >> 4) * 4;
      #pragma unroll
      for (int j = 0; j < 4; j++) {
        int row = rbase + j;
        float v = fmaxf(fmaf(acc[mi][ni][j], st.x, st.y), 0.f);
        int boff = row * 512 + ((((col >> 3) ^ (row & 7)) << 4) | ((col & 7) * 2));
        *(ushort_t*)(T_l + boff) = f2b(v);
      }
    }
  }
  #pragma unroll
  for (int mi = 0; mi < 4; mi++)
    #pragma unroll
    for (int ni = 0; ni < 4; ni++) acc[mi][ni] = (f32x4){0.f, 0.f, 0.f, 0.f};

  // ---- phase B: acc = T @ W2 ----
  for (int k0 = 0; k0 < CPAD; k0 += 64) {
    __syncthreads();   // waves done reading W_l (prev iter) / T written (first iter)
    #pragma unroll
    for (int c = 0; c < 8; c++) {
      int d = tid * 16 + c * 4096;
      int rowd = d >> 7, slot = (d >> 4) & 7, lslot = slot ^ (rowd & 7);
      gload_lds16((const char*)W2t + (size_t)rowd * 512 + k0 * 2 + lslot * 16, W_l + d);
    }
    __syncthreads();
    #pragma unroll
    for (int s = 0; s < 2; s++) {
      short8 bfr[4];
      #pragma unroll
      for (int ni = 0; ni < 4; ni++) {
        int brow = wn * 64 + ni * 16 + (lane & 15);
        int off = brow * 128 + (((s * 4 + (lane >> 4)) ^ (brow & 7)) << 4);
        bfr[ni] = *(const short8*)(W_l + off);
      }
      #pragma unroll
      for (int mi = 0; mi < 4; mi++) {
        int arow = mi * 16 + (lane & 15);
        int off = arow * 512 + k0 * 2 + (((s * 4 + (lane >> 4)) ^ (arow & 7)) << 4);
        short8 af = *(const short8*)(T_l + off);
        #pragma unroll
        for (int ni = 0; ni < 4; ni++)
          acc[mi][ni] = __builtin_amdgcn_mfma_f32_16x16x32_bf16(af, bfr[ni], acc[mi][ni], 0, 0, 0);
      }
    }
  }

  // ---- epilogue: X = relu(acc*s + t) (keep v in acc for pooling) ----
  #pragma unroll
  for (int ni = 0; ni < 4; ni++) {
    int col = wn * 64 + ni * 16 + (lane & 15);
    float2 st = ST2[col];
    #pragma unroll
    for (int mi = 0; mi < 4; mi++) {
      int rbase = mi * 16 + (lane >> 4) * 4;
      #pragma unroll
      for (int j = 0; j < 4; j++) {
        float v = fmaxf(fmaf(acc[mi][ni][j], st.x, st.y), 0.f);
        X[(r0 + rbase + j) * CPAD + col] = f2b(v);
        acc[mi][ni][j] = v;
      }
    }
  }

  // ---- fused per-graph pooling of this block's 64 output rows ----
  if (r0 < N_NODES) {
    int rlast = min((int)r0 + 63, N_NODES - 1);
    int gfirst = bv[r0], glast = bv[rlast];
    for (int g = gfirst; g <= glast; ++g) {
      int lo = max(gstart[g], (int)r0) - (int)r0;
      int hi = min(gstart[g + 1], (int)r0 + 64) - (int)r0;
      float ps[4];
      #pragma unroll
      for (int ni = 0; ni < 4; ni++) {
        float a = 0.f;
        #pragma unroll
        for (int mi = 0; mi < 4; mi++) {
          int rbase = mi * 16 + (lane >> 4) * 4;
          #pragma unroll
          for (int j = 0; j < 4; j++) {
            int row = rbase + j;
            a += (row >= lo && row < hi) ? acc[mi][ni][j] : 0.f;
          }
        }
        ps[ni] = a;
      }
      #pragma unroll
      for (int ni = 0; ni < 4; ni++) {
        ps[ni] += __shfl_xor(ps[ni], 16, 64);
        ps[ni] += __shfl_xor(ps[ni], 32, 64);
      }
      if (lane < 16) {
        #pragma unroll
        for (int ni = 0; ni < 4; ni++) {
          int col = wn * 64 + ni * 16 + lane;
          if (col < HID) atomicAdd(&pools_out[g * HID + col], ps[ni]);
        }
      }
    }
  }
}

// head stage 1: one block per (layer i, graph g)
__global__ void head1_kernel(const float* __restrict__ pools, const int* __restrict__ gstart,
                             const float* __restrict__ fcW, const float* __restrict__ fcb,
                             float* __restrict__ partial) {
  __shared__ float red[256];
  int i = blockIdx.x, g = blockIdx.y;
  int t = threadIdx.x;
  int o = t & 15, cg = t >> 4;
  const float* ps = pools + (size_t)(i * N_GRAPHS + g) * HID;
  const float* w = fcW + (size_t)i * HID * NUM_OUT;
  float a = 0.f;
  for (int c = cg; c < HID; c += 16) a = fmaf(ps[c], w[c * NUM_OUT + o], a);
  red[t] = a;
  __syncthreads();
  #pragma unroll
  for (int off = 8; off > 0; off >>= 1) {
    if (cg < off) red[t] += red[t + off * 16];
    __syncthreads();
  }
  if (cg == 0) {
    int cnt = gstart[g + 1] - gstart[g];
    float inv = 1.f / (float)(cnt > 0 ? cnt : 1);
    partial[(i * N_GRAPHS + g) * NUM_OUT + o] = red[t] * inv + fcb[i * NUM_OUT + o];
  }
}

// head stage 2: sum the 6 layer partials
__global__ void head2_kernel(const float* __restrict__ partial, float* __restrict__ out) {
  int t = threadIdx.x;
  if (t >= N_GRAPHS * NUM_OUT) return;
  float acc = 0.f;
  #pragma unroll
  for (int i = 0; i < NLAYERS + 1; ++i) acc += partial[i * N_GRAPHS * NUM_OUT + t];
  out[t] = acc;
}

// ---------------------------------------------------------------------------
extern "C" void kernel_launch(void* const* d_in, const int* in_sizes, int n_in,
                              void* d_out, int out_size, void* d_ws, size_t ws_size,
                              hipStream_t stream) {
  const int*   node_kind    = (const int*)d_in[0];
  const int*   node_content = (const int*)d_in[1];
  const int*   edge_index   = (const int*)d_in[2];
  const int*   edge_type    = (const int*)d_in[3];
  const int*   edge_pos     = (const int*)d_in[4];
  const int*   batch_vec    = (const int*)d_in[5];
  const float* kind_emb     = (const float*)d_in[6];
  const float* inst2vec     = (const float*)d_in[7];
  const float* type_emb     = (const float*)d_in[8];
  const float* etype_emb    = (const float*)d_in[9];
  const float* epos_emb     = (const float*)d_in[10];
  const float* W1   = (const float*)d_in[11];
  const float* b1   = (const float*)d_in[12];
  const float* bn_g = (const float*)d_in[13];
  const float* bn_b = (const float*)d_in[14];
  const float* bn_m = (const float*)d_in[15];
  const float* bn_v = (const float*)d_in[16];
  const float* W2   = (const float*)d_in[17];
  const float* b2   = (const float*)d_in[18];
  const float* fcW  = (const float*)d_in[19];
  const float* fcb  = (const float*)d_in[20];
  float* out = (float*)d_out;

  char* ws = (char*)d_ws;
  ushort_t* x     = (ushort_t*)(ws + 0ull);           // 25,624,576
  ushort_t* y     = (ushort_t*)(ws + 25624576ull);    // 25,624,576
  ushort_t* Wt    = (ushort_t*)(ws + 51249152ull);    // 1,310,720
  float2*   ST    = (float2*)  (ws + 52559872ull);    // 20,480
  float*    ecomb = (float*)   (ws + 52580352ull);    // 61*256*4 = 62,464
  int*      deg   = (int*)     (ws + 52642816ull);    // 200,000
  int*      offs  = (int*)     (ws + 52842816ull);    // 200,016
  int*      cursor= (int*)     (ws + 53042832ull);    // 200,000
  int*      e_pack= (int*)     (ws + 53242832ull);    // 2,400,000 (padded CSR)
  int*      gstart= (int*)     (ws + 55642832ull);    // 260
  float*    pools = (float*)   (ws + 55643092ull);    // 307,200
  int*      bsum  = (int*)     (ws + 55950292ull);    // 784
  int*      bpre  = (int*)     (ws + 55951076ull);    // 784
  float*    partial=(float*)   (ws + 55951860ull);    // 24,576

  const int* srcp = edge_index;
  const int* dstp = edge_index + N_EDGES;

  hipMemsetAsync(deg, 0, N_NODES * sizeof(int), stream);
  hipMemsetAsync(pools, 0, (NLAYERS + 1) * N_GRAPHS * HID * sizeof(float), stream);
  // zero pad rows of y once per launch (agg does not write them)
  hipMemsetAsync(y + (size_t)N_NODES * CPAD, 0, (size_t)(MPAD - N_NODES) * CPAD * 2, stream);

  prep_w<<<(10 * 256 * 256) / 256, 256, 0, stream>>>(W1, W2, Wt);
  prep_st<<<10, 256, 0, stream>>>(b1, bn_g, bn_b, bn_m, bn_v, b2, ST);
  ecomb_kernel<<<61, 256, 0, stream>>>(etype_emb, epos_emb, ecomb);
  embed_pool<<<MPAD / EROWS, 256, 0, stream>>>(node_kind, node_content, kind_emb, inst2vec,
                                               type_emb, batch_vec, x, pools);
  hist_kernel<<<(N_EDGES + 255) / 256, 256, 0, stream>>>(dstp, deg);
  scan1_kernel<<<SCAN_B, 256, 0, stream>>>(deg, bsum);
  scan2_kernel<<<1, 256, 0, stream>>>(bsum, bpre, offs, batch_vec, gstart);
  scan3_kernel<<<SCAN_B, 256, 0, stream>>>(deg, bpre, offs, cursor);
  scatter_kernel<<<(N_EDGES + 255) / 256, 256, 0, stream>>>(srcp, dstp, edge_type, edge_pos,
                                                            cursor, e_pack);
  fill_kernel<<<SCAN_B, 256, 0, stream>>>(cursor, offs, e_pack);

  const int fblocks = MPAD / 64;   // 782
  for (int i = 0; i < NLAYERS; ++i) {
    agg_kernel<<<(N_NODES + 3) / 4, 256, 0, stream>>>(x, y, offs, e_pack, ecomb);
    fused_layer<<<fblocks, 256, 0, stream>>>(y, x,
        Wt + (size_t)(2 * i) * 65536, Wt + (size_t)(2 * i + 1) * 65536,
        ST + (size_t)(2 * i) * 256, ST + (size_t)(2 * i + 1) * 256,
        batch_vec, gstart, pools + (size_t)(i + 1) * N_GRAPHS * HID);
  }
  head1_kernel<<<dim3(NLAYERS + 1, N_GRAPHS), 256, 0, stream>>>(pools, gstart, fcW, fcb, partial);
  head2_kernel<<<1, 1024, 0, stream>>>(partial, out);
}

// Round 7
// 446.509 us; speedup vs baseline: 5.5917x; 1.0129x over previous
//
#include <hip/hip_runtime.h>
#include <hip/hip_fp16.h>

#define N_NODES 50000
#define N_EDGES 400000
#define N_GRAPHS 64
#define HID 200
#define NUM_OUT 16
#define NLAYERS 5
#define CPAD 256            // padded channel count (K and N of GEMMs)
#define MPAD 50048          // padded row count (multiple of 64)
#define SCAN_B 196          // ceil(N_NODES/256)
#define EROWS 32            // rows per embed block

typedef unsigned short ushort_t;
typedef unsigned int uint_t;
typedef _Float16 half8 __attribute__((ext_vector_type(8)));
typedef float f32x4 __attribute__((ext_vector_type(4)));

__device__ __forceinline__ ushort_t f2h(float f) {
  return __half_as_ushort(__float2half(f));
}

// packed fp16 helpers (gfx950 v_pk ops)
__device__ __forceinline__ uint_t pk_add(uint_t a, uint_t b) {
  uint_t d; asm("v_pk_add_f16 %0, %1, %2" : "=v"(d) : "v"(a), "v"(b)); return d;
}
__device__ __forceinline__ uint_t pk_relu(uint_t a) {
  uint_t d; asm("v_pk_max_f16 %0, %1, 0" : "=v"(d) : "v"(a)); return d;
}

__device__ __forceinline__ void gload_lds16(const void* g, void* l) {
  __builtin_amdgcn_global_load_lds(
      (const __attribute__((address_space(1))) unsigned int*)g,
      (__attribute__((address_space(3))) unsigned int*)l, 16, 0, 0);
}

// ---------------------------------------------------------------------------
// embed + pool0 fused: 32 rows per block, thread = column (fp16 x out).
__global__ __launch_bounds__(256) void embed_pool(
    const int* __restrict__ kind, const int* __restrict__ content,
    const float* __restrict__ kind_emb, const float* __restrict__ inst2vec,
    const float* __restrict__ type_emb, const int* __restrict__ bv,
    ushort_t* __restrict__ x, float* __restrict__ pool0) {
  __shared__ int k_s[EROWS], c_s[EROWS], g_s[EROWS];
  int t = threadIdx.x;
  size_t r0 = (size_t)blockIdx.x * EROWS;
  if (t < EROWS) {
    size_t r = r0 + t;
    int k = 0, cn = 0, g = -1;
    if (r < N_NODES) { k = kind[r]; cn = content[r]; g = bv[r]; }
    k_s[t] = k; c_s[t] = cn; g_s[t] = g;
  }
  __syncthreads();
  int c = t;
  float pacc = 0.f; int gcur = -1;
  #pragma unroll 2
  for (int rr = 0; rr < EROWS; ++rr) {
    size_t r = r0 + rr;
    if (r < N_NODES) {
      float f = 0.f;
      if (c < HID) {
        int k = k_s[rr];
        f = kind_emb[k * HID + c] +
            ((k == 0) ? inst2vec[(size_t)c_s[rr] * HID + c] : type_emb[c]);
      }
      x[r * CPAD + c] = f2h(f);
      int g = g_s[rr];
      if (g != gcur) {
        if (gcur >= 0 && c < HID) atomicAdd(&pool0[gcur * HID + c], pacc);
        pacc = 0.f; gcur = g;
      }
      pacc += f;
    } else {
      x[r * CPAD + c] = 0;
    }
  }
  if (gcur >= 0 && c < HID) atomicAdd(&pool0[gcur * HID + c], pacc);
}

// edge-embedding table, packed fp16: ecomb[61][128] uints (=256 half channels).
// Row 60 = -65504 sentinel (dummy edges; relu clamps to 0).
__global__ void ecomb_kernel(const float* __restrict__ etype_emb, const float* __restrict__ epos_emb,
                             uint_t* __restrict__ ecomb) {
  int code = blockIdx.x; int cp = threadIdx.x;   // cp in [0,128)
  if (cp >= 128) return;
  uint_t v;
  if (code == 60) {
    v = 0xFBFFFBFFu;   // half -65504 in both halves
  } else {
    int c0 = cp * 2, c1 = cp * 2 + 1;
    float f0 = (c0 < HID) ? etype_emb[(code / 20) * HID + c0] + epos_emb[(code % 20) * HID + c0] : 0.f;
    float f1 = (c1 < HID) ? etype_emb[(code / 20) * HID + c1] + epos_emb[(code % 20) * HID + c1] : 0.f;
    v = (uint_t)f2h(f0) | ((uint_t)f2h(f1) << 16);
  }
  ecomb[code * 128 + cp] = v;
}

// weights: fp16, transposed, padded.  Wt[g][n][k], g=2i -> W1[i], g=2i+1 -> W2[i]
__global__ void prep_w(const float* __restrict__ W1, const float* __restrict__ W2,
                       ushort_t* __restrict__ Wt) {
  int idx = blockIdx.x * 256 + threadIdx.x;   // 10*256*256 total
  int g = idx >> 16; int rem = idx & 65535; int n = rem >> 8; int k = rem & 255;
  float v = 0.f;
  if (n < HID && k < HID) {
    int i = g >> 1;
    v = (g & 1) ? W2[(size_t)i * HID * HID + (size_t)k * HID + n]
                : W1[(size_t)i * HID * HID + (size_t)k * HID + n];
  }
  Wt[idx] = f2h(v);
}

// epilogue tables: out = relu(acc*s + t); pad channels s=t=0 (keeps pads zero)
__global__ void prep_st(const float* __restrict__ b1, const float* __restrict__ bn_g,
                        const float* __restrict__ bn_b, const float* __restrict__ bn_m,
                        const float* __restrict__ bn_v, const float* __restrict__ b2,
                        float2* __restrict__ ST) {
  int idx = blockIdx.x * 256 + threadIdx.x;   // 10*256
  int g = idx >> 8, c = idx & 255;
  float s = 0.f, t = 0.f;
  if (c < HID) {
    int i = g >> 1;
    if (g & 1) { s = 1.f; t = b2[i * HID + c]; }
    else {
      float sc = bn_g[i * HID + c] * rsqrtf(bn_v[i * HID + c] + 1e-5f);
      s = sc; t = (b1[i * HID + c] - bn_m[i * HID + c]) * sc + bn_b[i * HID + c];
    }
  }
  ST[idx] = make_float2(s, t);
}

// CSR build (padded degrees: multiple of 4)
__global__ void hist_kernel(const int* __restrict__ dst, int* __restrict__ deg) {
  int e = blockIdx.x * 256 + threadIdx.x;
  if (e < N_EDGES) atomicAdd(&deg[dst[e]], 1);
}

__global__ void scan1_kernel(const int* __restrict__ deg, int* __restrict__ bsum) {
  __shared__ int red[256];
  int b = blockIdx.x, t = threadIdx.x;
  int i = b * 256 + t;
  red[t] = (i < N_NODES) ? ((deg[i] + 3) & ~3) : 0;
  __syncthreads();
  for (int off = 128; off > 0; off >>= 1) {
    if (t < off) red[t] += red[t + off];
    __syncthreads();
  }
  if (t == 0) bsum[b] = red[0];
}

__global__ void scan2_kernel(const int* __restrict__ bsum, int* __restrict__ bpre,
                             int* __restrict__ offs, const int* __restrict__ bv,
                             int* __restrict__ gstart) {
  __shared__ int buf[256];
  int t = threadIdx.x;
  if (t <= N_GRAPHS) {
    if (t == N_GRAPHS) gstart[N_GRAPHS] = N_NODES;
    else {
      int lo = 0, hi = N_NODES;
      while (lo < hi) { int mid = (lo + hi) >> 1; if (bv[mid] < t) lo = mid + 1; else hi = mid; }
      gstart[t] = lo;
    }
  }
  int v = (t < SCAN_B) ? bsum[t] : 0;
  buf[t] = v;
  __syncthreads();
  for (int off = 1; off < 256; off <<= 1) {
    int tv = (t >= off) ? buf[t - off] : 0;
    __syncthreads();
    buf[t] += tv;
    __syncthreads();
  }
  if (t < SCAN_B) bpre[t] = buf[t] - v;
  if (t == 255) offs[N_NODES] = buf[255];
}

__global__ void scan3_kernel(const int* __restrict__ deg, const int* __restrict__ bpre,
                             int* __restrict__ offs, int* __restrict__ cursor) {
  __shared__ int buf[256];
  int b = blockIdx.x, t = threadIdx.x;
  int i = b * 256 + t;
  int v = (i < N_NODES) ? ((deg[i] + 3) & ~3) : 0;
  buf[t] = v;
  __syncthreads();
  for (int off = 1; off < 256; off <<= 1) {
    int tv = (t >= off) ? buf[t - off] : 0;
    __syncthreads();
    buf[t] += tv;
    __syncthreads();
  }
  if (i < N_NODES) {
    int e = bpre[b] + buf[t] - v;
    offs[i] = e; cursor[i] = e;
  }
}

// scatter real edges: pack (src,code) into one int
__global__ void scatter_kernel(const int* __restrict__ src, const int* __restrict__ dst,
                               const int* __restrict__ etype, const int* __restrict__ epos,
                               int* __restrict__ cursor, int* __restrict__ e_pack) {
  int e = blockIdx.x * 256 + threadIdx.x;
  if (e >= N_EDGES) return;
  int d = dst[e];
  int slot = atomicAdd(&cursor[d], 1);
  int p = epos[e]; if (p > 19) p = 19;
  e_pack[slot] = (src[e] << 6) | (etype[e] * 20 + p);
}

// fill padding slots with dummy edges: self-src + ecomb code 60 (-65504 -> relu 0)
__global__ void fill_kernel(const int* __restrict__ cursor, const int* __restrict__ offs,
                            int* __restrict__ e_pack) {
  int n = blockIdx.x * 256 + threadIdx.x;
  if (n >= N_NODES) return;
  int d = (n << 6) | 60;
  int e = offs[n + 1];
  for (int j = cursor[n]; j < e; ++j) e_pack[j] = d;
}

// GINE aggregation (fp16 packed math): one wave per 2 nodes, two interleaved
// edge streams for MLP; lanes 0..49 cover the 200 live channels (4 ch each).
__global__ __launch_bounds__(256) void agg_kernel(
    const ushort_t* __restrict__ x, ushort_t* __restrict__ y,
    const int* __restrict__ offs, const int* __restrict__ e_pack,
    const uint_t* __restrict__ ecomb) {
  int wid = threadIdx.x >> 6, lane = threadIdx.x & 63;
  int n0 = (blockIdx.x * 4 + wid) * 2;
  if (n0 >= N_NODES) return;
  int n1 = n0 + 1;   // N_NODES even -> always valid
  const uint2* xv = (const uint2*)x;     // 4 fp16 ch per lane
  const uint2* ecv = (const uint2*)ecomb;
  uint2* yv = (uint2*)y;
  if (lane >= 50) {
    yv[(size_t)n0 * 64 + lane] = make_uint2(0u, 0u);
    yv[(size_t)n1 * 64 + lane] = make_uint2(0u, 0u);
    return;
  }
  int j0 = offs[n0], e0 = offs[n0 + 1];
  int j1 = offs[n1], e1 = offs[n1 + 1];
  uint_t a0l = 0u, a0h = 0u, a1l = 0u, a1h = 0u;
  const int4* ep4 = (const int4*)e_pack;

  while ((j0 < e0) && (j1 < e1)) {
    int4 p0 = ep4[j0 >> 2];
    int4 p1 = ep4[j1 >> 2];
    j0 += 4; j1 += 4;
    uint2 xa0 = xv[(size_t)(p0.x >> 6) * 64 + lane];
    uint2 xa1 = xv[(size_t)(p0.y >> 6) * 64 + lane];
    uint2 xa2 = xv[(size_t)(p0.z >> 6) * 64 + lane];
    uint2 xa3 = xv[(size_t)(p0.w >> 6) * 64 + lane];
    uint2 xb0 = xv[(size_t)(p1.x >> 6) * 64 + lane];
    uint2 xb1 = xv[(size_t)(p1.y >> 6) * 64 + lane];
    uint2 xb2 = xv[(size_t)(p1.z >> 6) * 64 + lane];
    uint2 xb3 = xv[(size_t)(p1.w >> 6) * 64 + lane];
    uint2 ea0 = ecv[(size_t)(p0.x & 63) * 64 + lane];
    uint2 ea1 = ecv[(size_t)(p0.y & 63) * 64 + lane];
    uint2 ea2 = ecv[(size_t)(p0.z & 63) * 64 + lane];
    uint2 ea3 = ecv[(size_t)(p0.w & 63) * 64 + lane];
    uint2 eb0 = ecv[(size_t)(p1.x & 63) * 64 + lane];
    uint2 eb1 = ecv[(size_t)(p1.y & 63) * 64 + lane];
    uint2 eb2 = ecv[(size_t)(p1.z & 63) * 64 + lane];
    uint2 eb3 = ecv[(size_t)(p1.w & 63) * 64 + lane];
    a0l = pk_add(a0l, pk_relu(pk_add(xa0.x, ea0.x)));
    a0h = pk_add(a0h, pk_relu(pk_add(xa0.y, ea0.y)));
    a0l = pk_add(a0l, pk_relu(pk_add(xa1.x, ea1.x)));
    a0h = pk_add(a0h, pk_relu(pk_add(xa1.y, ea1.y)));
    a0l = pk_add(a0l, pk_relu(pk_add(xa2.x, ea2.x)));
    a0h = pk_add(a0h, pk_relu(pk_add(xa2.y, ea2.y)));
    a0l = pk_add(a0l, pk_relu(pk_add(xa3.x, ea3.x)));
    a0h = pk_add(a0h, pk_relu(pk_add(xa3.y, ea3.y)));
    a1l = pk_add(a1l, pk_relu(pk_add(xb0.x, eb0.x)));
    a1h = pk_add(a1h, pk_relu(pk_add(xb0.y, eb0.y)));
    a1l = pk_add(a1l, pk_relu(pk_add(xb1.x, eb1.x)));
    a1h = pk_add(a1h, pk_relu(pk_add(xb1.y, eb1.y)));
    a1l = pk_add(a1l, pk_relu(pk_add(xb2.x, eb2.x)));
    a1h = pk_add(a1h, pk_relu(pk_add(xb2.y, eb2.y)));
    a1l = pk_add(a1l, pk_relu(pk_add(xb3.x, eb3.x)));
    a1h = pk_add(a1h, pk_relu(pk_add(xb3.y, eb3.y)));
  }
  for (; j0 < e0; j0 += 4) {
    int4 p0 = ep4[j0 >> 2];
    uint2 xa0 = xv[(size_t)(p0.x >> 6) * 64 + lane];
    uint2 xa1 = xv[(size_t)(p0.y >> 6) * 64 + lane];
    uint2 xa2 = xv[(size_t)(p0.z >> 6) * 64 + lane];
    uint2 xa3 = xv[(size_t)(p0.w >> 6) * 64 + lane];
    uint2 ea0 = ecv[(size_t)(p0.x & 63) * 64 + lane];
    uint2 ea1 = ecv[(size_t)(p0.y & 63) * 64 + lane];
    uint2 ea2 = ecv[(size_t)(p0.z & 63) * 64 + lane];
    uint2 ea3 = ecv[(size_t)(p0.w & 63) * 64 + lane];
    a0l = pk_add(a0l, pk_relu(pk_add(xa0.x, ea0.x)));
    a0h = pk_add(a0h, pk_relu(pk_add(xa0.y, ea0.y)));
    a0l = pk_add(a0l, pk_relu(pk_add(xa1.x, ea1.x)));
    a0h = pk_add(a0h, pk_relu(pk_add(xa1.y, ea1.y)));
    a0l = pk_add(a0l, pk_relu(pk_add(xa2.x, ea2.x)));
    a0h = pk_add(a0h, pk_relu(pk_add(xa2.y, ea2.y)));
    a0l = pk_add(a0l, pk_relu(pk_add(xa3.x, ea3.x)));
    a0h = pk_add(a0h, pk_relu(pk_add(xa3.y, ea3.y)));
  }
  for (; j1 < e1; j1 += 4) {
    int4 p1 = ep4[j1 >> 2];
    uint2 xb0 = xv[(size_t)(p1.x >> 6) * 64 + lane];
    uint2 xb1 = xv[(size_t)(p1.y >> 6) * 64 + lane];
    uint2 xb2 = xv[(size_t)(p1.z >> 6) * 64 + lane];
    uint2 xb3 = xv[(size_t)(p1.w >> 6) * 64 + lane];
    uint2 eb0 = ecv[(size_t)(p1.x & 63) * 64 + lane];
    uint2 eb1 = ecv[(size_t)(p1.y & 63) * 64 + lane];
    uint2 eb2 = ecv[(size_t)(p1.z & 63) * 64 + lane];
    uint2 eb3 = ecv[(size_t)(p1.w & 63) * 64 + lane];
    a1l = pk_add(a1l, pk_relu(pk_add(xb0.x, eb0.x)));
    a1h = pk_add(a1h, pk_relu(pk_add(xb0.y, eb0.y)));
    a1l = pk_add(a1l, pk_relu(pk_add(xb1.x, eb1.x)));
    a1h = pk_add(a1h, pk_relu(pk_add(xb1.y, eb1.y)));
    a1l = pk_add(a1l, pk_relu(pk_add(xb2.x, eb2.x)));
    a1h = pk_add(a1h, pk_relu(pk_add(xb2.y, eb2.y)));
    a1l = pk_add(a1l, pk_relu(pk_add(xb3.x, eb3.x)));
    a1h = pk_add(a1h, pk_relu(pk_add(xb3.y, eb3.y)));
  }
  uint2 xn0 = xv[(size_t)n0 * 64 + lane];
  uint2 xn1 = xv[(size_t)n1 * 64 + lane];
  uint2 o0, o1;
  o0.x = pk_add(xn0.x, a0l); o0.y = pk_add(xn0.y, a0h);
  o1.x = pk_add(xn1.x, a1l); o1.y = pk_add(xn1.y, a1h);
  yv[(size_t)n0 * 64 + lane] = o0;
  yv[(size_t)n1 * 64 + lane] = o1;
}

// ---------------------------------------------------------------------------
// Fused layer (fp16): X = relu(relu(BN(Y@W1)) @ W2 + b2) + per-graph pooling.
__global__ __launch_bounds__(256, 2) void fused_layer(
    const ushort_t* __restrict__ Y, ushort_t* __restrict__ X,
    const ushort_t* __restrict__ W1t, const ushort_t* __restrict__ W2t,
    const float2* __restrict__ ST1, const float2* __restrict__ ST2,
    const int* __restrict__ bv, const int* __restrict__ gstart,
    float* __restrict__ pools_out) {
  __shared__ char lds[72 * 1024];
  char* A_l = lds;              //  8KB: 64 rows x 128B (A k-tile)
  char* W_l = lds + 8192;       // 32KB: 256 rows x 128B (W1/W2 k-tile)
  char* T_l = lds + 40960;      // 32KB: 64 rows x 512B (intermediate, swizzled)
  const int tid = threadIdx.x;
  const int lane = tid & 63, wn = tid >> 6;
  const size_t r0 = (size_t)blockIdx.x * 64;
  const char* Ab = (const char*)Y;

  f32x4 acc[4][4];
  #pragma unroll
  for (int mi = 0; mi < 4; mi++)
    #pragma unroll
    for (int ni = 0; ni < 4; ni++) acc[mi][ni] = (f32x4){0.f, 0.f, 0.f, 0.f};

  // ---- phase A: acc = Y_tile @ W1 ----
  for (int k0 = 0; k0 < CPAD; k0 += 64) {
    __syncthreads();
    #pragma unroll
    for (int c = 0; c < 2; c++) {
      int d = tid * 16 + c * 4096;
      int rowd = d >> 7, slot = (d >> 4) & 7, lslot = slot ^ (rowd & 7);
      gload_lds16(Ab + (r0 + rowd) * 512 + k0 * 2 + lslot * 16, A_l + d);
    }
    #pragma unroll
    for (int c = 0; c < 8; c++) {
      int d = tid * 16 + c * 4096;
      int rowd = d >> 7, slot = (d >> 4) & 7, lslot = slot ^ (rowd & 7);
      gload_lds16((const char*)W1t + (size_t)rowd * 512 + k0 * 2 + lslot * 16, W_l + d);
    }
    __syncthreads();
    #pragma unroll
    for (int s = 0; s < 2; s++) {
      half8 bfr[4];
      #pragma unroll
      for (int ni = 0; ni < 4; ni++) {
        int brow = wn * 64 + ni * 16 + (lane & 15);
        int off = brow * 128 + (((s * 4 + (lane >> 4)) ^ (brow & 7)) << 4);
        bfr[ni] = *(const half8*)(W_l + off);
      }
      #pragma unroll
      for (int mi = 0; mi < 4; mi++) {
        int arow = mi * 16 + (lane & 15);
        int off = arow * 128 + (((s * 4 + (lane >> 4)) ^ (arow & 7)) << 4);
        half8 af = *(const half8*)(A_l + off);
        #pragma unroll
        for (int ni = 0; ni < 4; ni++)
          acc[mi][ni] = __builtin_amdgcn_mfma_f32_16x16x32_f16(af, bfr[ni], acc[mi][ni], 0, 0, 0);
      }
    }
  }

  // ---- T = relu(BN(acc)) -> LDS (fp16, swizzled rows of 512B) ----
  #pragma unroll
  for (int ni = 0; ni < 4; ni++) {
    int col = wn * 64 + ni * 16 + (lane & 15);
    float2 st = ST1[col];
    #pragma unroll
    for (int mi = 0; mi < 4; mi++) {
      int rbase = mi * 16 + (lane >> 4) * 4;
      #pragma unroll
      for (int j = 0; j < 4; j++) {
        int row = rbase + j;
        float v = fmaxf(fmaf(acc[mi][ni][j], st.x, st.y), 0.f);
        int boff = row * 512 + ((((col >> 3) ^ (row & 7)) << 4) | ((col & 7) * 2));
        *(ushort_t*)(T_l + boff) = f2h(v);
      }
    }
  }
  #pragma unroll
  for (int mi = 0; mi < 4; mi++)
    #pragma unroll
    for (int ni = 0; ni < 4; ni++) acc[mi][ni] = (f32x4){0.f, 0.f, 0.f, 0.f};

  // ---- phase B: acc = T @ W2 ----
  for (int k0 = 0; k0 < CPAD; k0 += 64) {
    __syncthreads();
    #pragma unroll
    for (int c = 0; c < 8; c++) {
      int d = tid * 16 + c * 4096;
      int rowd = d >> 7, slot = (d >> 4) & 7, lslot = slot ^ (rowd & 7);
      gload_lds16((const char*)W2t + (size_t)rowd * 512 + k0 * 2 + lslot * 16, W_l + d);
    }
    __syncthreads();
    #pragma unroll
    for (int s = 0; s < 2; s++) {
      half8 bfr[4];
      #pragma unroll
      for (int ni = 0; ni < 4; ni++) {
        int brow = wn * 64 + ni * 16 + (lane & 15);
        int off = brow * 128 + (((s * 4 + (lane >> 4)) ^ (brow & 7)) << 4);
        bfr[ni] = *(const half8*)(W_l + off);
      }
      #pragma unroll
      for (int mi = 0; mi < 4; mi++) {
        int arow = mi * 16 + (lane & 15);
        int off = arow * 512 + k0 * 2 + (((s * 4 + (lane >> 4)) ^ (arow & 7)) << 4);
        half8 af = *(const half8*)(T_l + off);
        #pragma unroll
        for (int ni = 0; ni < 4; ni++)
          acc[mi][ni] = __builtin_amdgcn_mfma_f32_16x16x32_f16(af, bfr[ni], acc[mi][ni], 0, 0, 0);
      }
    }
  }

  // ---- epilogue: X = relu(acc*s + t) (keep v in acc for pooling) ----
  #pragma unroll
  for (int ni = 0; ni < 4; ni++) {
    int col = wn * 64 + ni * 16 + (lane & 15);
    float2 st = ST2[col];
    #pragma unroll
    for (int mi = 0; mi < 4; mi++) {
      int rbase = mi * 16 + (lane >> 4) * 4;
      #pragma unroll
      for (int j = 0; j < 4; j++) {
        float v = fmaxf(fmaf(acc[mi][ni][j], st.x, st.y), 0.f);
        X[(r0 + rbase + j) * CPAD + col] = f2h(v);
        acc[mi][ni][j] = v;
      }
    }
  }

  // ---- fused per-graph pooling of this block's 64 output rows ----
  if (r0 < N_NODES) {
    int rlast = min((int)r0 + 63, N_NODES - 1);
    int gfirst = bv[r0], glast = bv[rlast];
    for (int g = gfirst; g <= glast; ++g) {
      int lo = max(gstart[g], (int)r0) - (int)r0;
      int hi = min(gstart[g + 1], (int)r0 + 64) - (int)r0;
      float ps[4];
      #pragma unroll
      for (int ni = 0; ni < 4; ni++) {
        float a = 0.f;
        #pragma unroll
        for (int mi = 0; mi < 4; mi++) {
          int rbase = mi * 16 + (lane >> 4) * 4;
          #pragma unroll
          for (int j = 0; j < 4; j++) {
            int row = rbase + j;
            a += (row >= lo && row < hi) ? acc[mi][ni][j] : 0.f;
          }
        }
        ps[ni] = a;
      }
      #pragma unroll
      for (int ni = 0; ni < 4; ni++) {
        ps[ni] += __shfl_xor(ps[ni], 16, 64);
        ps[ni] += __shfl_xor(ps[ni], 32, 64);
      }
      if (lane < 16) {
        #pragma unroll
        for (int ni = 0; ni < 4; ni++) {
          int col = wn * 64 + ni * 16 + lane;
          if (col < HID) atomicAdd(&pools_out[g * HID + col], ps[ni]);
        }
      }
    }
  }
}

// head stage 1: one block per (layer i, graph g)
__global__ void head1_kernel(const float* __restrict__ pools, const int* __restrict__ gstart,
                             const float* __restrict__ fcW, const float* __restrict__ fcb,
                             float* __restrict__ partial) {
  __shared__ float red[256];
  int i = blockIdx.x, g = blockIdx.y;
  int t = threadIdx.x;
  int o = t & 15, cg = t >> 4;
  const float* ps = pools + (size_t)(i * N_GRAPHS + g) * HID;
  const float* w = fcW + (size_t)i * HID * NUM_OUT;
  float a = 0.f;
  for (int c = cg; c < HID; c += 16) a = fmaf(ps[c], w[c * NUM_OUT + o], a);
  red[t] = a;
  __syncthreads();
  #pragma unroll
  for (int off = 8; off > 0; off >>= 1) {
    if (cg < off) red[t] += red[t + off * 16];
    __syncthreads();
  }
  if (cg == 0) {
    int cnt = gstart[g + 1] - gstart[g];
    float inv = 1.f / (float)(cnt > 0 ? cnt : 1);
    partial[(i * N_GRAPHS + g) * NUM_OUT + o] = red[t] * inv + fcb[i * NUM_OUT + o];
  }
}

// head stage 2: sum the 6 layer partials
__global__ void head2_kernel(const float* __restrict__ partial, float* __restrict__ out) {
  int t = threadIdx.x;
  if (t >= N_GRAPHS * NUM_OUT) return;
  float acc = 0.f;
  #pragma unroll
  for (int i = 0; i < NLAYERS + 1; ++i) acc += partial[i * N_GRAPHS * NUM_OUT + t];
  out[t] = acc;
}

// ---------------------------------------------------------------------------
extern "C" void kernel_launch(void* const* d_in, const int* in_sizes, int n_in,
                              void* d_out, int out_size, void* d_ws, size_t ws_size,
                              hipStream_t stream) {
  const int*   node_kind    = (const int*)d_in[0];
  const int*   node_content = (const int*)d_in[1];
  const int*   edge_index   = (const int*)d_in[2];
  const int*   edge_type    = (const int*)d_in[3];
  const int*   edge_pos     = (const int*)d_in[4];
  const int*   batch_vec    = (const int*)d_in[5];
  const float* kind_emb     = (const float*)d_in[6];
  const float* inst2vec     = (const float*)d_in[7];
  const float* type_emb     = (const float*)d_in[8];
  const float* etype_emb    = (const float*)d_in[9];
  const float* epos_emb     = (const float*)d_in[10];
  const float* W1   = (const float*)d_in[11];
  const float* b1   = (const float*)d_in[12];
  const float* bn_g = (const float*)d_in[13];
  const float* bn_b = (const float*)d_in[14];
  const float* bn_m = (const float*)d_in[15];
  const float* bn_v = (const float*)d_in[16];
  const float* W2   = (const float*)d_in[17];
  const float* b2   = (const float*)d_in[18];
  const float* fcW  = (const float*)d_in[19];
  const float* fcb  = (const float*)d_in[20];
  float* out = (float*)d_out;

  char* ws = (char*)d_ws;
  ushort_t* x     = (ushort_t*)(ws + 0ull);           // 25,624,576
  ushort_t* y     = (ushort_t*)(ws + 25624576ull);    // 25,624,576
  ushort_t* Wt    = (ushort_t*)(ws + 51249152ull);    // 1,310,720
  float2*   ST    = (float2*)  (ws + 52559872ull);    // 20,480
  uint_t*   ecomb = (uint_t*)  (ws + 52580352ull);    // 61*512 = 31,232
  int*      deg   = (int*)     (ws + 52642816ull);    // 200,000
  int*      offs  = (int*)     (ws + 52842816ull);    // 200,016
  int*      cursor= (int*)     (ws + 53042832ull);    // 200,000
  int*      e_pack= (int*)     (ws + 53242832ull);    // 2,400,000 (padded CSR)
  int*      gstart= (int*)     (ws + 55642832ull);    // 260
  float*    pools = (float*)   (ws + 55643092ull);    // 307,200
  int*      bsum  = (int*)     (ws + 55950292ull);    // 784
  int*      bpre  = (int*)     (ws + 55951076ull);    // 784
  float*    partial=(float*)   (ws + 55951860ull);    // 24,576

  const int* srcp = edge_index;
  const int* dstp = edge_index + N_EDGES;

  hipMemsetAsync(deg, 0, N_NODES * sizeof(int), stream);
  hipMemsetAsync(pools, 0, (NLAYERS + 1) * N_GRAPHS * HID * sizeof(float), stream);
  // zero pad rows of y once per launch (agg does not write them)
  hipMemsetAsync(y + (size_t)N_NODES * CPAD, 0, (size_t)(MPAD - N_NODES) * CPAD * 2, stream);

  prep_w<<<(10 * 256 * 256) / 256, 256, 0, stream>>>(W1, W2, Wt);
  prep_st<<<10, 256, 0, stream>>>(b1, bn_g, bn_b, bn_m, bn_v, b2, ST);
  ecomb_kernel<<<61, 128, 0, stream>>>(etype_emb, epos_emb, ecomb);
  embed_pool<<<MPAD / EROWS, 256, 0, stream>>>(node_kind, node_content, kind_emb, inst2vec,
                                               type_emb, batch_vec, x, pools);
  hist_kernel<<<(N_EDGES + 255) / 256, 256, 0, stream>>>(dstp, deg);
  scan1_kernel<<<SCAN_B, 256, 0, stream>>>(deg, bsum);
  scan2_kernel<<<1, 256, 0, stream>>>(bsum, bpre, offs, batch_vec, gstart);
  scan3_kernel<<<SCAN_B, 256, 0, stream>>>(deg, bpre, offs, cursor);
  scatter_kernel<<<(N_EDGES + 255) / 256, 256, 0, stream>>>(srcp, dstp, edge_type, edge_pos,
                                                            cursor, e_pack);
  fill_kernel<<<SCAN_B, 256, 0, stream>>>(cursor, offs, e_pack);

  const int fblocks = MPAD / 64;   // 782
  const int ablocks = (N_NODES / 2 + 3) / 4;   // 6250
  for (int i = 0; i < NLAYERS; ++i) {
    agg_kernel<<<ablocks, 256, 0, stream>>>(x, y, offs, e_pack, ecomb);
    fused_layer<<<fblocks, 256, 0, stream>>>(y, x,
        Wt + (size_t)(2 * i) * 65536, Wt + (size_t)(2 * i + 1) * 65536,
        ST + (size_t)(2 * i) * 256, ST + (size_t)(2 * i + 1) * 256,
        batch_vec, gstart, pools + (size_t)(i + 1) * N_GRAPHS * HID);
  }
  head1_kernel<<<dim3(NLAYERS + 1, N_GRAPHS), 256, 0, stream>>>(pools, gstart, fcW, fcb, partial);
  head2_kernel<<<1, 1024, 0, stream>>>(partial, out);
}

// Round 8
// 444.493 us; speedup vs baseline: 5.6170x; 1.0045x over previous
//
#include <hip/hip_runtime.h>
#include <hip/hip_fp16.h>

#define N_NODES 50000
#define N_EDGES 400000
#define N_GRAPHS 64
#define HID 200
#define NUM_OUT 16
#define NLAYERS 5
#define CPAD 256            // padded channel count (K and N of GEMMs)
#define MPAD 50048          // padded row count (multiple of 64)
#define SCAN_B 196          // ceil(N_NODES/256)
#define EROWS 32            // rows per embed block

typedef unsigned short ushort_t;
typedef unsigned int uint_t;
typedef _Float16 half8 __attribute__((ext_vector_type(8)));
typedef float f32x4 __attribute__((ext_vector_type(4)));

__device__ __forceinline__ ushort_t f2h(float f) {
  return __half_as_ushort(__float2half(f));
}

// packed fp16 helpers
__device__ __forceinline__ uint_t pk_add(uint_t a, uint_t b) {
  uint_t d; asm("v_pk_add_f16 %0, %1, %2" : "=v"(d) : "v"(a), "v"(b)); return d;
}
__device__ __forceinline__ uint_t pk_relu(uint_t a) {
  uint_t d; asm("v_pk_max_f16 %0, %1, 0" : "=v"(d) : "v"(a)); return d;
}

__device__ __forceinline__ void gload_lds16(const void* g, void* l) {
  __builtin_amdgcn_global_load_lds(
      (const __attribute__((address_space(1))) unsigned int*)g,
      (__attribute__((address_space(3))) unsigned int*)l, 16, 0, 0);
}

// ---------------------------------------------------------------------------
// embed + pool0 fused: 32 rows per block, thread = column (fp16 x out).
__global__ __launch_bounds__(256) void embed_pool(
    const int* __restrict__ kind, const int* __restrict__ content,
    const float* __restrict__ kind_emb, const float* __restrict__ inst2vec,
    const float* __restrict__ type_emb, const int* __restrict__ bv,
    ushort_t* __restrict__ x, float* __restrict__ pool0) {
  __shared__ int k_s[EROWS], c_s[EROWS], g_s[EROWS];
  int t = threadIdx.x;
  size_t r0 = (size_t)blockIdx.x * EROWS;
  if (t < EROWS) {
    size_t r = r0 + t;
    int k = 0, cn = 0, g = -1;
    if (r < N_NODES) { k = kind[r]; cn = content[r]; g = bv[r]; }
    k_s[t] = k; c_s[t] = cn; g_s[t] = g;
  }
  __syncthreads();
  int c = t;
  float pacc = 0.f; int gcur = -1;
  #pragma unroll 2
  for (int rr = 0; rr < EROWS; ++rr) {
    size_t r = r0 + rr;
    if (r < N_NODES) {
      float f = 0.f;
      if (c < HID) {
        int k = k_s[rr];
        f = kind_emb[k * HID + c] +
            ((k == 0) ? inst2vec[(size_t)c_s[rr] * HID + c] : type_emb[c]);
      }
      x[r * CPAD + c] = f2h(f);
      int g = g_s[rr];
      if (g != gcur) {
        if (gcur >= 0 && c < HID) atomicAdd(&pool0[gcur * HID + c], pacc);
        pacc = 0.f; gcur = g;
      }
      pacc += f;
    } else {
      x[r * CPAD + c] = 0;
    }
  }
  if (gcur >= 0 && c < HID) atomicAdd(&pool0[gcur * HID + c], pacc);
}

// edge-embedding table, packed fp16: ecomb[61][128] uints (=256 half channels).
// Row 60 = -65504 sentinel (dummy edges; relu clamps to 0).
__global__ void ecomb_kernel(const float* __restrict__ etype_emb, const float* __restrict__ epos_emb,
                             uint_t* __restrict__ ecomb) {
  int code = blockIdx.x; int cp = threadIdx.x;   // cp in [0,128)
  if (cp >= 128) return;
  uint_t v;
  if (code == 60) {
    v = 0xFBFFFBFFu;   // half -65504 in both halves
  } else {
    int c0 = cp * 2, c1 = cp * 2 + 1;
    float f0 = (c0 < HID) ? etype_emb[(code / 20) * HID + c0] + epos_emb[(code % 20) * HID + c0] : 0.f;
    float f1 = (c1 < HID) ? etype_emb[(code / 20) * HID + c1] + epos_emb[(code % 20) * HID + c1] : 0.f;
    v = (uint_t)f2h(f0) | ((uint_t)f2h(f1) << 16);
  }
  ecomb[code * 128 + cp] = v;
}

// weights: fp16, transposed, padded.  Wt[g][n][k], g=2i -> W1[i], g=2i+1 -> W2[i]
__global__ void prep_w(const float* __restrict__ W1, const float* __restrict__ W2,
                       ushort_t* __restrict__ Wt) {
  int idx = blockIdx.x * 256 + threadIdx.x;   // 10*256*256 total
  int g = idx >> 16; int rem = idx & 65535; int n = rem >> 8; int k = rem & 255;
  float v = 0.f;
  if (n < HID && k < HID) {
    int i = g >> 1;
    v = (g & 1) ? W2[(size_t)i * HID * HID + (size_t)k * HID + n]
                : W1[(size_t)i * HID * HID + (size_t)k * HID + n];
  }
  Wt[idx] = f2h(v);
}

// epilogue tables: out = relu(acc*s + t); pad channels s=t=0 (keeps pads zero)
__global__ void prep_st(const float* __restrict__ b1, const float* __restrict__ bn_g,
                        const float* __restrict__ bn_b, const float* __restrict__ bn_m,
                        const float* __restrict__ bn_v, const float* __restrict__ b2,
                        float2* __restrict__ ST) {
  int idx = blockIdx.x * 256 + threadIdx.x;   // 10*256
  int g = idx >> 8, c = idx & 255;
  float s = 0.f, t = 0.f;
  if (c < HID) {
    int i = g >> 1;
    if (g & 1) { s = 1.f; t = b2[i * HID + c]; }
    else {
      float sc = bn_g[i * HID + c] * rsqrtf(bn_v[i * HID + c] + 1e-5f);
      s = sc; t = (b1[i * HID + c] - bn_m[i * HID + c]) * sc + bn_b[i * HID + c];
    }
  }
  ST[idx] = make_float2(s, t);
}

// CSR build (padded degrees: multiple of 4)
__global__ void hist_kernel(const int* __restrict__ dst, int* __restrict__ deg) {
  int e = blockIdx.x * 256 + threadIdx.x;
  if (e < N_EDGES) atomicAdd(&deg[dst[e]], 1);
}

__global__ void scan1_kernel(const int* __restrict__ deg, int* __restrict__ bsum) {
  __shared__ int red[256];
  int b = blockIdx.x, t = threadIdx.x;
  int i = b * 256 + t;
  red[t] = (i < N_NODES) ? ((deg[i] + 3) & ~3) : 0;
  __syncthreads();
  for (int off = 128; off > 0; off >>= 1) {
    if (t < off) red[t] += red[t + off];
    __syncthreads();
  }
  if (t == 0) bsum[b] = red[0];
}

__global__ void scan2_kernel(const int* __restrict__ bsum, int* __restrict__ bpre,
                             int* __restrict__ offs, const int* __restrict__ bv,
                             int* __restrict__ gstart) {
  __shared__ int buf[256];
  int t = threadIdx.x;
  if (t <= N_GRAPHS) {
    if (t == N_GRAPHS) gstart[N_GRAPHS] = N_NODES;
    else {
      int lo = 0, hi = N_NODES;
      while (lo < hi) { int mid = (lo + hi) >> 1; if (bv[mid] < t) lo = mid + 1; else hi = mid; }
      gstart[t] = lo;
    }
  }
  int v = (t < SCAN_B) ? bsum[t] : 0;
  buf[t] = v;
  __syncthreads();
  for (int off = 1; off < 256; off <<= 1) {
    int tv = (t >= off) ? buf[t - off] : 0;
    __syncthreads();
    buf[t] += tv;
    __syncthreads();
  }
  if (t < SCAN_B) bpre[t] = buf[t] - v;
  if (t == 255) offs[N_NODES] = buf[255];
}

__global__ void scan3_kernel(const int* __restrict__ deg, const int* __restrict__ bpre,
                             int* __restrict__ offs, int* __restrict__ cursor) {
  __shared__ int buf[256];
  int b = blockIdx.x, t = threadIdx.x;
  int i = b * 256 + t;
  int v = (i < N_NODES) ? ((deg[i] + 3) & ~3) : 0;
  buf[t] = v;
  __syncthreads();
  for (int off = 1; off < 256; off <<= 1) {
    int tv = (t >= off) ? buf[t - off] : 0;
    __syncthreads();
    buf[t] += tv;
    __syncthreads();
  }
  if (i < N_NODES) {
    int e = bpre[b] + buf[t] - v;
    offs[i] = e; cursor[i] = e;
  }
}

// scatter real edges: pack (src,code) into one int
__global__ void scatter_kernel(const int* __restrict__ src, const int* __restrict__ dst,
                               const int* __restrict__ etype, const int* __restrict__ epos,
                               int* __restrict__ cursor, int* __restrict__ e_pack) {
  int e = blockIdx.x * 256 + threadIdx.x;
  if (e >= N_EDGES) return;
  int d = dst[e];
  int slot = atomicAdd(&cursor[d], 1);
  int p = epos[e]; if (p > 19) p = 19;
  e_pack[slot] = (src[e] << 6) | (etype[e] * 20 + p);
}

// fill padding slots with dummy edges: src = node 0 (L1-hot row) + sentinel
// code 60 (-65504 -> relu 0 regardless of x[0]).
__global__ void fill_kernel(const int* __restrict__ cursor, const int* __restrict__ offs,
                            int* __restrict__ e_pack) {
  int n = blockIdx.x * 256 + threadIdx.x;
  if (n >= N_NODES) return;
  int e = offs[n + 1];
  for (int j = cursor[n]; j < e; ++j) e_pack[j] = 60;   // (0<<6)|60
}

// GINE aggregation (fp16 packed math): one wave per 2 nodes, two interleaved
// edge streams; lanes 0..49 cover the 200 live channels (4 ch each).
__global__ __launch_bounds__(256) void agg_kernel(
    const ushort_t* __restrict__ x, ushort_t* __restrict__ y,
    const int* __restrict__ offs, const int* __restrict__ e_pack,
    const uint_t* __restrict__ ecomb) {
  int wid = threadIdx.x >> 6, lane = threadIdx.x & 63;
  int n0 = (blockIdx.x * 4 + wid) * 2;
  if (n0 >= N_NODES) return;
  int n1 = n0 + 1;   // N_NODES even -> always valid
  const uint2* xv = (const uint2*)x;     // 4 fp16 ch per lane
  const uint2* ecv = (const uint2*)ecomb;
  uint2* yv = (uint2*)y;
  if (lane >= 50) {
    yv[(size_t)n0 * 64 + lane] = make_uint2(0u, 0u);
    yv[(size_t)n1 * 64 + lane] = make_uint2(0u, 0u);
    return;
  }
  int j0 = offs[n0], e0 = offs[n0 + 1];
  int j1 = offs[n1], e1 = offs[n1 + 1];
  uint_t a0l = 0u, a0h = 0u, a1l = 0u, a1h = 0u;
  const int4* ep4 = (const int4*)e_pack;

  while ((j0 < e0) && (j1 < e1)) {
    int4 p0 = ep4[j0 >> 2];
    int4 p1 = ep4[j1 >> 2];
    j0 += 4; j1 += 4;
    uint2 xa0 = xv[(size_t)(p0.x >> 6) * 64 + lane];
    uint2 xa1 = xv[(size_t)(p0.y >> 6) * 64 + lane];
    uint2 xa2 = xv[(size_t)(p0.z >> 6) * 64 + lane];
    uint2 xa3 = xv[(size_t)(p0.w >> 6) * 64 + lane];
    uint2 xb0 = xv[(size_t)(p1.x >> 6) * 64 + lane];
    uint2 xb1 = xv[(size_t)(p1.y >> 6) * 64 + lane];
    uint2 xb2 = xv[(size_t)(p1.z >> 6) * 64 + lane];
    uint2 xb3 = xv[(size_t)(p1.w >> 6) * 64 + lane];
    uint2 ea0 = ecv[(size_t)(p0.x & 63) * 64 + lane];
    uint2 ea1 = ecv[(size_t)(p0.y & 63) * 64 + lane];
    uint2 ea2 = ecv[(size_t)(p0.z & 63) * 64 + lane];
    uint2 ea3 = ecv[(size_t)(p0.w & 63) * 64 + lane];
    uint2 eb0 = ecv[(size_t)(p1.x & 63) * 64 + lane];
    uint2 eb1 = ecv[(size_t)(p1.y & 63) * 64 + lane];
    uint2 eb2 = ecv[(size_t)(p1.z & 63) * 64 + lane];
    uint2 eb3 = ecv[(size_t)(p1.w & 63) * 64 + lane];
    a0l = pk_add(a0l, pk_relu(pk_add(xa0.x, ea0.x)));
    a0h = pk_add(a0h, pk_relu(pk_add(xa0.y, ea0.y)));
    a0l = pk_add(a0l, pk_relu(pk_add(xa1.x, ea1.x)));
    a0h = pk_add(a0h, pk_relu(pk_add(xa1.y, ea1.y)));
    a0l = pk_add(a0l, pk_relu(pk_add(xa2.x, ea2.x)));
    a0h = pk_add(a0h, pk_relu(pk_add(xa2.y, ea2.y)));
    a0l = pk_add(a0l, pk_relu(pk_add(xa3.x, ea3.x)));
    a0h = pk_add(a0h, pk_relu(pk_add(xa3.y, ea3.y)));
    a1l = pk_add(a1l, pk_relu(pk_add(xb0.x, eb0.x)));
    a1h = pk_add(a1h, pk_relu(pk_add(xb0.y, eb0.y)));
    a1l = pk_add(a1l, pk_relu(pk_add(xb1.x, eb1.x)));
    a1h = pk_add(a1h, pk_relu(pk_add(xb1.y, eb1.y)));
    a1l = pk_add(a1l, pk_relu(pk_add(xb2.x, eb2.x)));
    a1h = pk_add(a1h, pk_relu(pk_add(xb2.y, eb2.y)));
    a1l = pk_add(a1l, pk_relu(pk_add(xb3.x, eb3.x)));
    a1h = pk_add(a1h, pk_relu(pk_add(xb3.y, eb3.y)));
  }
  for (; j0 < e0; j0 += 4) {
    int4 p0 = ep4[j0 >> 2];
    uint2 xa0 = xv[(size_t)(p0.x >> 6) * 64 + lane];
    uint2 xa1 = xv[(size_t)(p0.y >> 6) * 64 + lane];
    uint2 xa2 = xv[(size_t)(p0.z >> 6) * 64 + lane];
    uint2 xa3 = xv[(size_t)(p0.w >> 6) * 64 + lane];
    uint2 ea0 = ecv[(size_t)(p0.x & 63) * 64 + lane];
    uint2 ea1 = ecv[(size_t)(p0.y & 63) * 64 + lane];
    uint2 ea2 = ecv[(size_t)(p0.z & 63) * 64 + lane];
    uint2 ea3 = ecv[(size_t)(p0.w & 63) * 64 + lane];
    a0l = pk_add(a0l, pk_relu(pk_add(xa0.x, ea0.x)));
    a0h = pk_add(a0h, pk_relu(pk_add(xa0.y, ea0.y)));
    a0l = pk_add(a0l, pk_relu(pk_add(xa1.x, ea1.x)));
    a0h = pk_add(a0h, pk_relu(pk_add(xa1.y, ea1.y)));
    a0l = pk_add(a0l, pk_relu(pk_add(xa2.x, ea2.x)));
    a0h = pk_add(a0h, pk_relu(pk_add(xa2.y, ea2.y)));
    a0l = pk_add(a0l, pk_relu(pk_add(xa3.x, ea3.x)));
    a0h = pk_add(a0h, pk_relu(pk_add(xa3.y, ea3.y)));
  }
  for (; j1 < e1; j1 += 4) {
    int4 p1 = ep4[j1 >> 2];
    uint2 xb0 = xv[(size_t)(p1.x >> 6) * 64 + lane];
    uint2 xb1 = xv[(size_t)(p1.y >> 6) * 64 + lane];
    uint2 xb2 = xv[(size_t)(p1.z >> 6) * 64 + lane];
    uint2 xb3 = xv[(size_t)(p1.w >> 6) * 64 + lane];
    uint2 eb0 = ecv[(size_t)(p1.x & 63) * 64 + lane];
    uint2 eb1 = ecv[(size_t)(p1.y & 63) * 64 + lane];
    uint2 eb2 = ecv[(size_t)(p1.z & 63) * 64 + lane];
    uint2 eb3 = ecv[(size_t)(p1.w & 63) * 64 + lane];
    a1l = pk_add(a1l, pk_relu(pk_add(xb0.x, eb0.x)));
    a1h = pk_add(a1h, pk_relu(pk_add(xb0.y, eb0.y)));
    a1l = pk_add(a1l, pk_relu(pk_add(xb1.x, eb1.x)));
    a1h = pk_add(a1h, pk_relu(pk_add(xb1.y, eb1.y)));
    a1l = pk_add(a1l, pk_relu(pk_add(xb2.x, eb2.x)));
    a1h = pk_add(a1h, pk_relu(pk_add(xb2.y, eb2.y)));
    a1l = pk_add(a1l, pk_relu(pk_add(xb3.x, eb3.x)));
    a1h = pk_add(a1h, pk_relu(pk_add(xb3.y, eb3.y)));
  }
  uint2 xn0 = xv[(size_t)n0 * 64 + lane];
  uint2 xn1 = xv[(size_t)n1 * 64 + lane];
  uint2 o0, o1;
  o0.x = pk_add(xn0.x, a0l); o0.y = pk_add(xn0.y, a0h);
  o1.x = pk_add(xn1.x, a1l); o1.y = pk_add(xn1.y, a1h);
  yv[(size_t)n0 * 64 + lane] = o0;
  yv[(size_t)n1 * 64 + lane] = o1;
}

// ---------------------------------------------------------------------------
// Fused layer (fp16): X = relu(relu(BN(Y@W1)) @ W2 + b2) + per-graph pooling.
// 2-phase counted-vmcnt pipeline: A tile double-buffered; stage-W-then-
// prefetch-A order so vmcnt(2) leaves the next A tile in flight.
__global__ __launch_bounds__(256, 2) void fused_layer(
    const ushort_t* __restrict__ Y, ushort_t* __restrict__ X,
    const ushort_t* __restrict__ W1t, const ushort_t* __restrict__ W2t,
    const float2* __restrict__ ST1, const float2* __restrict__ ST2,
    const int* __restrict__ bv, const int* __restrict__ gstart,
    float* __restrict__ pools_out) {
  __shared__ char lds[80 * 1024];
  char* A_l0 = lds;             //  8KB: 64 rows x 128B (A k-tile, buf 0)
  char* A_l1 = lds + 8192;      //  8KB: buf 1
  char* W_l  = lds + 16384;     // 32KB: 256 rows x 128B (W1/W2 k-tile)
  char* T_l  = lds + 49152;     // 32KB: 64 rows x 512B (intermediate, swizzled)
  const int tid = threadIdx.x;
  const int lane = tid & 63, wn = tid >> 6;
  const size_t r0 = (size_t)blockIdx.x * 64;
  const char* Ab = (const char*)Y;
  const char* W1c = (const char*)W1t;
  const char* W2c = (const char*)W2t;

  f32x4 acc[4][4];
  #pragma unroll
  for (int mi = 0; mi < 4; mi++)
    #pragma unroll
    for (int ni = 0; ni < 4; ni++) acc[mi][ni] = (f32x4){0.f, 0.f, 0.f, 0.f};

  // ---- phase A: acc = Y_tile @ W1, pipelined ----
  {
    // prologue: prefetch A(0) into buf0
    #pragma unroll
    for (int c = 0; c < 2; c++) {
      int d = tid * 16 + c * 4096;
      int rowd = d >> 7, slot = (d >> 4) & 7, lslot = slot ^ (rowd & 7);
      gload_lds16(Ab + (r0 + rowd) * 512 + 0 + lslot * 16, A_l0 + d);
    }
    #pragma unroll
    for (int t = 0; t < 4; ++t) {
      const int k0 = t * 64;
      // stage W1(t) into W_l (safe: trailing barrier of t-1 passed)
      #pragma unroll
      for (int c = 0; c < 8; c++) {
        int d = tid * 16 + c * 4096;
        int rowd = d >> 7, slot = (d >> 4) & 7, lslot = slot ^ (rowd & 7);
        gload_lds16(W1c + (size_t)rowd * 512 + k0 * 2 + lslot * 16, W_l + d);
      }
      // prefetch A(t+1) into the other buffer
      if (t < 3) {
        char* nbuf = (t & 1) ? A_l0 : A_l1;
        #pragma unroll
        for (int c = 0; c < 2; c++) {
          int d = tid * 16 + c * 4096;
          int rowd = d >> 7, slot = (d >> 4) & 7, lslot = slot ^ (rowd & 7);
          gload_lds16(Ab + (r0 + rowd) * 512 + (k0 + 64) * 2 + lslot * 16, nbuf + d);
        }
        asm volatile("s_waitcnt vmcnt(2)" ::: "memory");   // W(t)+A(t) done, A(t+1) in flight
      } else {
        asm volatile("s_waitcnt vmcnt(0)" ::: "memory");
      }
      __builtin_amdgcn_sched_barrier(0);
      __builtin_amdgcn_s_barrier();
      const char* Abuf = (t & 1) ? A_l1 : A_l0;
      #pragma unroll
      for (int s = 0; s < 2; s++) {
        half8 bfr[4];
        #pragma unroll
        for (int ni = 0; ni < 4; ni++) {
          int brow = wn * 64 + ni * 16 + (lane & 15);
          int off = brow * 128 + (((s * 4 + (lane >> 4)) ^ (brow & 7)) << 4);
          bfr[ni] = *(const half8*)(W_l + off);
        }
        #pragma unroll
        for (int mi = 0; mi < 4; mi++) {
          int arow = mi * 16 + (lane & 15);
          int off = arow * 128 + (((s * 4 + (lane >> 4)) ^ (arow & 7)) << 4);
          half8 af = *(const half8*)(Abuf + off);
          #pragma unroll
          for (int ni = 0; ni < 4; ni++)
            acc[mi][ni] = __builtin_amdgcn_mfma_f32_16x16x32_f16(af, bfr[ni], acc[mi][ni], 0, 0, 0);
        }
      }
      __builtin_amdgcn_s_barrier();   // all waves done reading W_l before t+1 overwrites
    }
  }

  // ---- T = relu(BN(acc)) -> LDS (fp16, swizzled rows of 512B) ----
  #pragma unroll
  for (int ni = 0; ni < 4; ni++) {
    int col = wn * 64 + ni * 16 + (lane & 15);
    float2 st = ST1[col];
    #pragma unroll
    for (int mi = 0; mi < 4; mi++) {
      int rbase = mi * 16 + (lane >> 4) * 4;
      #pragma unroll
      for (int j = 0; j < 4; j++) {
        int row = rbase + j;
        float v = fmaxf(fmaf(acc[mi][ni][j], st.x, st.y), 0.f);
        int boff = row * 512 + ((((col >> 3) ^ (row & 7)) << 4) | ((col & 7) * 2));
        *(ushort_t*)(T_l + boff) = f2h(v);
      }
    }
  }
  #pragma unroll
  for (int mi = 0; mi < 4; mi++)
    #pragma unroll
    for (int ni = 0; ni < 4; ni++) acc[mi][ni] = (f32x4){0.f, 0.f, 0.f, 0.f};
  __syncthreads();   // T visible to all waves

  // ---- phase B: acc = T @ W2 (W2 L2-hot; simple stage/drain per k-tile) ----
  #pragma unroll
  for (int t = 0; t < 4; ++t) {
    const int k0 = t * 64;
    #pragma unroll
    for (int c = 0; c < 8; c++) {
      int d = tid * 16 + c * 4096;
      int rowd = d >> 7, slot = (d >> 4) & 7, lslot = slot ^ (rowd & 7);
      gload_lds16(W2c + (size_t)rowd * 512 + k0 * 2 + lslot * 16, W_l + d);
    }
    asm volatile("s_waitcnt vmcnt(0)" ::: "memory");
    __builtin_amdgcn_sched_barrier(0);
    __builtin_amdgcn_s_barrier();
    #pragma unroll
    for (int s = 0; s < 2; s++) {
      half8 bfr[4];
      #pragma unroll
      for (int ni = 0; ni < 4; ni++) {
        int brow = wn * 64 + ni * 16 + (lane & 15);
        int off = brow * 128 + (((s * 4 + (lane >> 4)) ^ (brow & 7)) << 4);
        bfr[ni] = *(const half8*)(W_l + off);
      }
      #pragma unroll
      for (int mi = 0; mi < 4; mi++) {
        int arow = mi * 16 + (lane & 15);
        int off = arow * 512 + k0 * 2 + (((s * 4 + (lane >> 4)) ^ (arow & 7)) << 4);
        half8 af = *(const half8*)(T_l + off);
        #pragma unroll
        for (int ni = 0; ni < 4; ni++)
          acc[mi][ni] = __builtin_amdgcn_mfma_f32_16x16x32_f16(af, bfr[ni], acc[mi][ni], 0, 0, 0);
      }
    }
    __builtin_amdgcn_s_barrier();
  }

  // ---- epilogue: X = relu(acc*s + t) (keep v in acc for pooling) ----
  #pragma unroll
  for (int ni = 0; ni < 4; ni++) {
    int col = wn * 64 + ni * 16 + (lane & 15);
    float2 st = ST2[col];
    #pragma unroll
    for (int mi = 0; mi < 4; mi++) {
      int rbase = mi * 16 + (lane >> 4) * 4;
      #pragma unroll
      for (int j = 0; j < 4; j++) {
        float v = fmaxf(fmaf(acc[mi][ni][j], st.x, st.y), 0.f);
        X[(r0 + rbase + j) * CPAD + col] = f2h(v);
        acc[mi][ni][j] = v;
      }
    }
  }

  // ---- fused per-graph pooling of this block's 64 output rows ----
  if (r0 < N_NODES) {
    int rlast = min((int)r0 + 63, N_NODES - 1);
    int gfirst = bv[r0], glast = bv[rlast];
    for (int g = gfirst; g <= glast; ++g) {
      int lo = max(gstart[g], (int)r0) - (int)r0;
      int hi = min(gstart[g + 1], (int)r0 + 64) - (int)r0;
      float ps[4];
      #pragma unroll
      for (int ni = 0; ni < 4; ni++) {
        float a = 0.f;
        #pragma unroll
        for (int mi = 0; mi < 4; mi++) {
          int rbase = mi * 16 + (lane >> 4) * 4;
          #pragma unroll
          for (int j = 0; j < 4; j++) {
            int row = rbase + j;
            a += (row >= lo && row < hi) ? acc[mi][ni][j] : 0.f;
          }
        }
        ps[ni] = a;
      }
      #pragma unroll
      for (int ni = 0; ni < 4; ni++) {
        ps[ni] += __shfl_xor(ps[ni], 16, 64);
        ps[ni] += __shfl_xor(ps[ni], 32, 64);
      }
      if (lane < 16) {
        #pragma unroll
        for (int ni = 0; ni < 4; ni++) {
          int col = wn * 64 + ni * 16 + lane;
          if (col < HID) atomicAdd(&pools_out[g * HID + col], ps[ni]);
        }
      }
    }
  }
}

// head stage 1: one block per (layer i, graph g)
__global__ void head1_kernel(const float* __restrict__ pools, const int* __restrict__ gstart,
                             const float* __restrict__ fcW, const float* __restrict__ fcb,
                             float* __restrict__ partial) {
  __shared__ float red[256];
  int i = blockIdx.x, g = blockIdx.y;
  int t = threadIdx.x;
  int o = t & 15, cg = t >> 4;
  const float* ps = pools + (size_t)(i * N_GRAPHS + g) * HID;
  const float* w = fcW + (size_t)i * HID * NUM_OUT;
  float a = 0.f;
  for (int c = cg; c < HID; c += 16) a = fmaf(ps[c], w[c * NUM_OUT + o], a);
  red[t] = a;
  __syncthreads();
  #pragma unroll
  for (int off = 8; off > 0; off >>= 1) {
    if (cg < off) red[t] += red[t + off * 16];
    __syncthreads();
  }
  if (cg == 0) {
    int cnt = gstart[g + 1] - gstart[g];
    float inv = 1.f / (float)(cnt > 0 ? cnt : 1);
    partial[(i * N_GRAPHS + g) * NUM_OUT + o] = red[t] * inv + fcb[i * NUM_OUT + o];
  }
}

// head stage 2: sum the 6 layer partials
__global__ void head2_kernel(const float* __restrict__ partial, float* __restrict__ out) {
  int t = threadIdx.x;
  if (t >= N_GRAPHS * NUM_OUT) return;
  float acc = 0.f;
  #pragma unroll
  for (int i = 0; i < NLAYERS + 1; ++i) acc += partial[i * N_GRAPHS * NUM_OUT + t];
  out[t] = acc;
}

// ---------------------------------------------------------------------------
extern "C" void kernel_launch(void* const* d_in, const int* in_sizes, int n_in,
                              void* d_out, int out_size, void* d_ws, size_t ws_size,
                              hipStream_t stream) {
  const int*   node_kind    = (const int*)d_in[0];
  const int*   node_content = (const int*)d_in[1];
  const int*   edge_index   = (const int*)d_in[2];
  const int*   edge_type    = (const int*)d_in[3];
  const int*   edge_pos     = (const int*)d_in[4];
  const int*   batch_vec    = (const int*)d_in[5];
  const float* kind_emb     = (const float*)d_in[6];
  const float* inst2vec     = (const float*)d_in[7];
  const float* type_emb     = (const float*)d_in[8];
  const float* etype_emb    = (const float*)d_in[9];
  const float* epos_emb     = (const float*)d_in[10];
  const float* W1   = (const float*)d_in[11];
  const float* b1   = (const float*)d_in[12];
  const float* bn_g = (const float*)d_in[13];
  const float* bn_b = (const float*)d_in[14];
  const float* bn_m = (const float*)d_in[15];
  const float* bn_v = (const float*)d_in[16];
  const float* W2   = (const float*)d_in[17];
  const float* b2   = (const float*)d_in[18];
  const float* fcW  = (const float*)d_in[19];
  const float* fcb  = (const float*)d_in[20];
  float* out = (float*)d_out;

  char* ws = (char*)d_ws;
  ushort_t* x     = (ushort_t*)(ws + 0ull);           // 25,624,576
  ushort_t* y     = (ushort_t*)(ws + 25624576ull);    // 25,624,576
  ushort_t* Wt    = (ushort_t*)(ws + 51249152ull);    // 1,310,720
  float2*   ST    = (float2*)  (ws + 52559872ull);    // 20,480
  uint_t*   ecomb = (uint_t*)  (ws + 52580352ull);    // 61*512 = 31,232
  int*      deg   = (int*)     (ws + 52642816ull);    // 200,000
  int*      offs  = (int*)     (ws + 52842816ull);    // 200,016
  int*      cursor= (int*)     (ws + 53042832ull);    // 200,000
  int*      e_pack= (int*)     (ws + 53242832ull);    // 2,400,000 (padded CSR)
  int*      gstart= (int*)     (ws + 55642832ull);    // 260
  float*    pools = (float*)   (ws + 55643092ull);    // 307,200
  int*      bsum  = (int*)     (ws + 55950292ull);    // 784
  int*      bpre  = (int*)     (ws + 55951076ull);    // 784
  float*    partial=(float*)   (ws + 55951860ull);    // 24,576

  const int* srcp = edge_index;
  const int* dstp = edge_index + N_EDGES;

  hipMemsetAsync(deg, 0, N_NODES * sizeof(int), stream);
  hipMemsetAsync(pools, 0, (NLAYERS + 1) * N_GRAPHS * HID * sizeof(float), stream);
  // zero pad rows of y once per launch (agg does not write them)
  hipMemsetAsync(y + (size_t)N_NODES * CPAD, 0, (size_t)(MPAD - N_NODES) * CPAD * 2, stream);

  prep_w<<<(10 * 256 * 256) / 256, 256, 0, stream>>>(W1, W2, Wt);
  prep_st<<<10, 256, 0, stream>>>(b1, bn_g, bn_b, bn_m, bn_v, b2, ST);
  ecomb_kernel<<<61, 128, 0, stream>>>(etype_emb, epos_emb, ecomb);
  embed_pool<<<MPAD / EROWS, 256, 0, stream>>>(node_kind, node_content, kind_emb, inst2vec,
                                               type_emb, batch_vec, x, pools);
  hist_kernel<<<(N_EDGES + 255) / 256, 256, 0, stream>>>(dstp, deg);
  scan1_kernel<<<SCAN_B, 256, 0, stream>>>(deg, bsum);
  scan2_kernel<<<1, 256, 0, stream>>>(bsum, bpre, offs, batch_vec, gstart);
  scan3_kernel<<<SCAN_B, 256, 0, stream>>>(deg, bpre, offs, cursor);
  scatter_kernel<<<(N_EDGES + 255) / 256, 256, 0, stream>>>(srcp, dstp, edge_type, edge_pos,
                                                            cursor, e_pack);
  fill_kernel<<<SCAN_B, 256, 0, stream>>>(cursor, offs, e_pack);

  const int fblocks = MPAD / 64;   // 782
  const int ablocks = (N_NODES / 2 + 3) / 4;   // 6250
  for (int i = 0; i < NLAYERS; ++i) {
    agg_kernel<<<ablocks, 256, 0, stream>>>(x, y, offs, e_pack, ecomb);
    fused_layer<<<fblocks, 256, 0, stream>>>(y, x,
        Wt + (size_t)(2 * i) * 65536, Wt + (size_t)(2 * i + 1) * 65536,
        ST + (size_t)(2 * i) * 256, ST + (size_t)(2 * i + 1) * 256,
        batch_vec, gstart, pools + (size_t)(i + 1) * N_GRAPHS * HID);
  }
  head1_kernel<<<dim3(NLAYERS + 1, N_GRAPHS), 256, 0, stream>>>(pools, gstart, fcW, fcb, partial);
  head2_kernel<<<1, 1024, 0, stream>>>(partial, out);
}